// Round 9
// baseline (433.989 us; speedup 1.0000x reference)
//
#include <hip/hip_runtime.h>
#include <math.h>

#define NHID 128
#define NFEAT 256
#define NCLASS 40

typedef __bf16 bf16x8 __attribute__((ext_vector_type(8)));
typedef __bf16 bf16x4 __attribute__((ext_vector_type(4)));
typedef float floatx4 __attribute__((ext_vector_type(4)));

// ===========================================================================
// CSR build via 2-level bucketed counting sort (r5-verified kernels).
// Bucket = dst >> 8; record = (dst&255)<<16 | src  (N <= 65536).
// ===========================================================================

__global__ __launch_bounds__(256) void bucket_hist(const int* __restrict__ edst,
                                                   int* __restrict__ bucket_counts,
                                                   int E, int nbuck) {
    __shared__ int lh[256];
    int tid = threadIdx.x;
    lh[tid] = 0;
    __syncthreads();
    int base = blockIdx.x * 4096;
#pragma unroll
    for (int k = 0; k < 16; ++k) {
        int e = base + k * 256 + tid;
        if (e < E) atomicAdd(&lh[edst[e] >> 8], 1);
    }
    __syncthreads();
    if (tid < nbuck && lh[tid]) atomicAdd(&bucket_counts[tid], lh[tid]);
}

__global__ __launch_bounds__(256) void bucket_scan(const int* __restrict__ counts,
                                                   int* __restrict__ start,
                                                   int* __restrict__ cursor,
                                                   int* __restrict__ row_ptr,
                                                   int nbuck, int E, int N) {
    __shared__ int lds[256];
    int tid = threadIdx.x;
    int v = (tid < nbuck) ? counts[tid] : 0;
    lds[tid] = v;
    __syncthreads();
    for (int off = 1; off < 256; off <<= 1) {
        int t = (tid >= off) ? lds[tid - off] : 0;
        __syncthreads();
        lds[tid] += t;
        __syncthreads();
    }
    int excl = lds[tid] - v;
    if (tid < nbuck) { start[tid] = excl; cursor[tid] = excl; }
    if (tid == 0) { start[nbuck] = E; row_ptr[N] = E; }
}

__global__ __launch_bounds__(256) void bucket_scatter(const int* __restrict__ esrc,
                                                      const int* __restrict__ edst,
                                                      int* __restrict__ cursor,
                                                      unsigned int* __restrict__ bdata,
                                                      int E, int nbuck) {
    __shared__ int lh[256];
    __shared__ int lbase[256];
    int tid = threadIdx.x;
    lh[tid] = 0;
    __syncthreads();
    int base = blockIdx.x * 4096;
    unsigned int recs[16];
    short bks[16];
    short lofs[16];
#pragma unroll
    for (int k = 0; k < 16; ++k) {
        int e = base + k * 256 + tid;
        bks[k] = -1;
        if (e < E) {
            int d = edst[e];
            int s = esrc[e];
            int b = d >> 8;
            recs[k] = ((unsigned int)(d & 255) << 16) | (unsigned int)s;
            bks[k] = (short)b;
            lofs[k] = (short)atomicAdd(&lh[b], 1);
        }
    }
    __syncthreads();
    if (tid < nbuck && lh[tid]) lbase[tid] = atomicAdd(&cursor[tid], lh[tid]);
    __syncthreads();
#pragma unroll
    for (int k = 0; k < 16; ++k) {
        if (bks[k] >= 0) bdata[lbase[bks[k]] + lofs[k]] = recs[k];
    }
}

__global__ __launch_bounds__(256) void bucket_finalize(const unsigned int* __restrict__ bdata,
                                                       const int* __restrict__ start,
                                                       int* __restrict__ row_ptr,
                                                       int* __restrict__ srcs,
                                                       int N) {
    __shared__ int hist[256];
    __shared__ int cur[256];
    int b = blockIdx.x;
    int tid = threadIdx.x;
    int s0 = start[b];
    int cnt = start[b + 1] - s0;
    hist[tid] = 0;
    __syncthreads();
    for (int i = tid; i < cnt; i += 256) atomicAdd(&hist[bdata[s0 + i] >> 16], 1);
    __syncthreads();
    int v0 = hist[tid];
    __syncthreads();
    for (int off = 1; off < 256; off <<= 1) {
        int t = (tid >= off) ? hist[tid - off] : 0;
        __syncthreads();
        hist[tid] += t;
        __syncthreads();
    }
    int excl = hist[tid] - v0;
    cur[tid] = excl;
    int node = b * 256 + tid;
    if (node < N) row_ptr[node] = s0 + excl;
    __syncthreads();
    for (int i = tid; i < cnt; i += 256) {
        unsigned int r = bdata[s0 + i];
        int p = atomicAdd(&cur[r >> 16], 1);
        srcs[s0 + p] = (int)(r & 0xffffu);
    }
}

// ===========================================================================
// Weight prep (single dispatch): transpose + split fp32 W[K][128] ->
// Wt_hi/lo[128][K] bf16, for W_in (K=256) and the 3 W_mlps (K=128).
// ===========================================================================
__global__ __launch_bounds__(256) void transpose_split_all(
    const float* __restrict__ Win, const float* __restrict__ Wmlps,
    __bf16* __restrict__ dInHi, __bf16* __restrict__ dInLo,
    __bf16* __restrict__ dMlHi, __bf16* __restrict__ dMlLo) {
    const int TOT_IN = 128 * NFEAT;      // 32768
    const int TOT_ML = 3 * 128 * NHID;   // 49152
    int i = blockIdx.x * 256 + threadIdx.x;
    if (i < TOT_IN) {
        int n = i / NFEAT;
        int k = i - n * NFEAT;
        float v = Win[(size_t)k * 128 + n];
        __bf16 h = (__bf16)v;
        dInHi[i] = h;
        dInLo[i] = (__bf16)(v - (float)h);
    } else if (i < TOT_IN + TOT_ML) {
        int r = i - TOT_IN;
        int per = 128 * NHID;
        int l = r / per;
        int rr = r - l * per;
        int n = rr / NHID;
        int k = rr - n * NHID;
        float v = Wmlps[(size_t)l * per + (size_t)k * 128 + n];
        __bf16 h = (__bf16)v;
        dMlHi[r] = h;
        dMlLo[r] = (__bf16)(v - (float)h);
    }
}

// ===========================================================================
// Fused aggregate (r5-verified): sum = h[node](hi+lo) + sum_{src} h_hi[src].
// One wave/node; 16 lanes x 16B row; 16 edges (4 gathers) in flight.
// ===========================================================================
__global__ __launch_bounds__(256) void aggregate_fused(const __bf16* __restrict__ hhi,
                                                       const __bf16* __restrict__ hlo,
                                                       const int* __restrict__ row_ptr,
                                                       const int* __restrict__ srcs,
                                                       __bf16* __restrict__ ohi,
                                                       __bf16* __restrict__ olo, int N) {
    int tid = threadIdx.x;
    int node = blockIdx.x * 4 + (tid >> 6);
    if (node >= N) return;
    int lane = tid & 63;
    int g = lane >> 4;
    int c = lane & 15;
    int beg = row_ptr[node];
    int end = row_ptr[node + 1];
    const bf16x8* hv = (const bf16x8*)hhi;

    bf16x8 sh = hv[(size_t)node * 16 + c];
    bf16x8 sl = ((const bf16x8*)hlo)[(size_t)node * 16 + c];

    float a[8], b2[8];
#pragma unroll
    for (int j = 0; j < 8; ++j) { a[j] = 0.f; b2[j] = 0.f; }

    int i = beg;
    for (; i + 16 <= end; i += 16) {
        int s0 = __builtin_nontemporal_load(&srcs[i + g]);
        int s1 = __builtin_nontemporal_load(&srcs[i + 4 + g]);
        int s2 = __builtin_nontemporal_load(&srcs[i + 8 + g]);
        int s3 = __builtin_nontemporal_load(&srcs[i + 12 + g]);
        bf16x8 v0 = hv[(size_t)s0 * 16 + c];
        bf16x8 v1 = hv[(size_t)s1 * 16 + c];
        bf16x8 v2 = hv[(size_t)s2 * 16 + c];
        bf16x8 v3 = hv[(size_t)s3 * 16 + c];
#pragma unroll
        for (int j = 0; j < 8; ++j) {
            a[j] += (float)v0[j] + (float)v2[j];
            b2[j] += (float)v1[j] + (float)v3[j];
        }
    }
    for (; i + 8 <= end; i += 8) {
        int s0 = __builtin_nontemporal_load(&srcs[i + g]);
        int s1 = __builtin_nontemporal_load(&srcs[i + 4 + g]);
        bf16x8 v0 = hv[(size_t)s0 * 16 + c];
        bf16x8 v1 = hv[(size_t)s1 * 16 + c];
#pragma unroll
        for (int j = 0; j < 8; ++j) { a[j] += (float)v0[j]; b2[j] += (float)v1[j]; }
    }
    for (; i < end; i += 4) {
        if (i + g < end) {
            int s = __builtin_nontemporal_load(&srcs[i + g]);
            bf16x8 v = hv[(size_t)s * 16 + c];
#pragma unroll
            for (int j = 0; j < 8; ++j) a[j] += (float)v[j];
        }
    }
#pragma unroll
    for (int j = 0; j < 8; ++j) a[j] += b2[j];
#pragma unroll
    for (int j = 0; j < 8; ++j) a[j] += __shfl_xor(a[j], 16);
#pragma unroll
    for (int j = 0; j < 8; ++j) a[j] += __shfl_xor(a[j], 32);

    if (g == 0) {
        bf16x8 whi, wlo;
#pragma unroll
        for (int j = 0; j < 8; ++j) {
            float v = a[j] + (float)sh[j] + (float)sl[j];
            __bf16 h = (__bf16)v;
            whi[j] = h;
            wlo[j] = (__bf16)(v - (float)h);
        }
        ((bf16x8*)ohi)[(size_t)node * 16 + c] = whi;
        ((bf16x8*)olo)[(size_t)node * 16 + c] = wlo;
    }
}

// ===========================================================================
// DIRECT-OPERAND MFMA GEMM: out = relu(A @ W + b), 128 cols, bf16 hi/lo split.
// No k-loop LDS, no k-loop barriers: A fragments are per-wave-private rows
// read straight from global (L2/L3-resident); W fragments are read straight
// from global (shared across all blocks -> L1/L2-hot). k-loop fully unrolled.
// LDS = 16KB epilogue buffer only -> 8 blocks/CU (100% wave occupancy).
// Logical fragment layout (equal to old swizzled version, XOR cancels):
//   A[row0+wave*16+m16][k0 + s*32 + q*8], W^T[t*16+m16][k0 + s*32 + q*8].
// MODE 0: A = fp32 (K=256), split hi/lo in registers. MODE 1: bf16 pair.
// ===========================================================================
template <int MODE, int K>
__global__ __launch_bounds__(256) void gemm_direct(
    const float* __restrict__ Af, const __bf16* __restrict__ Ahi,
    const __bf16* __restrict__ Alo,
    const __bf16* __restrict__ Wthi, const __bf16* __restrict__ Wtlo,
    const float* __restrict__ bias, __bf16* __restrict__ Ohi,
    __bf16* __restrict__ Olo, int M) {
    __shared__ __align__(16) float eps[32 * 128];  // 16KB two-pass epilogue
    int tid = threadIdx.x;
    int row0 = blockIdx.x * 64;
    int wave = tid >> 6;
    int l = tid & 63;
    int m16 = l & 15;
    int q = l >> 4;
    int garow = min(row0 + wave * 16 + m16, M - 1);

    floatx4 acc[8];
#pragma unroll
    for (int t = 0; t < 8; ++t) acc[t] = (floatx4){0.f, 0.f, 0.f, 0.f};

#pragma unroll
    for (int k0 = 0; k0 < K; k0 += 64) {
#pragma unroll
        for (int s = 0; s < 2; ++s) {
            int kk = k0 + s * 32 + q * 8;
            bf16x8 ahi, alo;
            if (MODE == 0) {
                float4 v0 = *(const float4*)&Af[(size_t)garow * K + kk];
                float4 v1 = *(const float4*)&Af[(size_t)garow * K + kk + 4];
                float sv[8] = {v0.x, v0.y, v0.z, v0.w, v1.x, v1.y, v1.z, v1.w};
#pragma unroll
                for (int j = 0; j < 8; ++j) {
                    __bf16 h = (__bf16)sv[j];
                    ahi[j] = h;
                    alo[j] = (__bf16)(sv[j] - (float)h);
                }
            } else {
                ahi = *(const bf16x8*)&Ahi[(size_t)garow * K + kk];
                alo = *(const bf16x8*)&Alo[(size_t)garow * K + kk];
            }
#pragma unroll
            for (int t = 0; t < 8; ++t) {
                int n = t * 16 + m16;
                bf16x8 bhi = *(const bf16x8*)&Wthi[(size_t)n * K + kk];
                bf16x8 blo = *(const bf16x8*)&Wtlo[(size_t)n * K + kk];
                acc[t] = __builtin_amdgcn_mfma_f32_16x16x32_bf16(ahi, bhi, acc[t], 0, 0, 0);
                acc[t] = __builtin_amdgcn_mfma_f32_16x16x32_bf16(alo, bhi, acc[t], 0, 0, 0);
                acc[t] = __builtin_amdgcn_mfma_f32_16x16x32_bf16(ahi, blo, acc[t], 0, 0, 0);
            }
        }
    }

    // ---- two-pass epilogue: 32 rows at a time through 16KB LDS ----
#pragma unroll
    for (int half = 0; half < 2; ++half) {
        if ((wave >> 1) == half) {
#pragma unroll
            for (int t = 0; t < 8; ++t) {
                int col = t * 16 + m16;
                float bb = bias[col];
#pragma unroll
                for (int i = 0; i < 4; ++i) {
                    int lr = (wave & 1) * 16 + q * 4 + i;  // 0..31 within half
                    eps[lr * 128 + col] = fmaxf(acc[t][i] + bb, 0.f);
                }
            }
        }
        __syncthreads();
#pragma unroll
        for (int it = 0; it < 4; ++it) {
            int lin = it * 1024 + tid * 4;
            int row = lin >> 7, col = lin & 127;
            int g = row0 + half * 32 + row;
            if (g < M) {
                float4 v = *(float4*)(eps + lin);
                bf16x4 hi, lo;
                float vv[4] = {v.x, v.y, v.z, v.w};
#pragma unroll
                for (int j = 0; j < 4; ++j) {
                    __bf16 h = (__bf16)vv[j];
                    hi[j] = h;
                    lo[j] = (__bf16)(vv[j] - (float)h);
                }
                *(bf16x4*)&Ohi[(size_t)g * 128 + col] = hi;
                *(bf16x4*)&Olo[(size_t)g * 128 + col] = lo;
            }
        }
        __syncthreads();
    }
}

// ===========================================================================
// Final layer: direct-operand GEMM (K=128) + fused output layer + log_softmax.
// h' = relu(A @ W + b) staged 32 rows at a time in LDS; logits = h'@W_out+b;
// out = log_softmax. LDS = eps32(16.9K) + W_out(20.5K) + b(0.2K) ~ 37.6KB.
// ===========================================================================
__global__ __launch_bounds__(256) void gemm_out_direct(
    const __bf16* __restrict__ Ahi, const __bf16* __restrict__ Alo,
    const __bf16* __restrict__ Wthi, const __bf16* __restrict__ Wtlo,
    const float* __restrict__ bias,
    const float* __restrict__ Wout, const float* __restrict__ bout,
    float* __restrict__ out, int M) {
    __shared__ __align__(16) char smem[37664];
    float* eps = (float*)smem;                 // 32*132*4 = 16896
    float* sWo = (float*)(smem + 16896);       // 128*40*4 = 20480
    float* sb  = (float*)(smem + 37376);       // 160
    int tid = threadIdx.x;
    int row0 = blockIdx.x * 64;
    int wave = tid >> 6;
    int l = tid & 63;
    int m16 = l & 15;
    int q = l >> 4;
    int garow = min(row0 + wave * 16 + m16, M - 1);

    floatx4 acc[8];
#pragma unroll
    for (int t = 0; t < 8; ++t) acc[t] = (floatx4){0.f, 0.f, 0.f, 0.f};

#pragma unroll
    for (int k0 = 0; k0 < 128; k0 += 64) {
#pragma unroll
        for (int s = 0; s < 2; ++s) {
            int kk = k0 + s * 32 + q * 8;
            bf16x8 ahi = *(const bf16x8*)&Ahi[(size_t)garow * 128 + kk];
            bf16x8 alo = *(const bf16x8*)&Alo[(size_t)garow * 128 + kk];
#pragma unroll
            for (int t = 0; t < 8; ++t) {
                int n = t * 16 + m16;
                bf16x8 bhi = *(const bf16x8*)&Wthi[(size_t)n * 128 + kk];
                bf16x8 blo = *(const bf16x8*)&Wtlo[(size_t)n * 128 + kk];
                acc[t] = __builtin_amdgcn_mfma_f32_16x16x32_bf16(ahi, bhi, acc[t], 0, 0, 0);
                acc[t] = __builtin_amdgcn_mfma_f32_16x16x32_bf16(alo, bhi, acc[t], 0, 0, 0);
                acc[t] = __builtin_amdgcn_mfma_f32_16x16x32_bf16(ahi, blo, acc[t], 0, 0, 0);
            }
        }
    }

    // stage W_out / b_out
    for (int i = tid; i < 128 * NCLASS; i += 256) sWo[i] = Wout[i];
    if (tid < NCLASS) sb[tid] = bout[tid];

    // ---- two-pass: relu rows -> eps -> logits + log_softmax ----
#pragma unroll
    for (int half = 0; half < 2; ++half) {
        if ((wave >> 1) == half) {
#pragma unroll
            for (int t = 0; t < 8; ++t) {
                int col = t * 16 + m16;
                float bb = bias[col];
#pragma unroll
                for (int i = 0; i < 4; ++i) {
                    int lr = (wave & 1) * 16 + q * 4 + i;  // 0..31
                    eps[lr * 132 + col] = fmaxf(acc[t][i] + bb, 0.f);
                }
            }
        }
        __syncthreads();
        // 8 threads/row, 5 classes/thread (proven r5 pattern)
        int r = tid >> 3;
        int cg = tid & 7;
        float z[5];
#pragma unroll
        for (int j = 0; j < 5; ++j) z[j] = sb[cg * 5 + j];
        for (int k = 0; k < 128; ++k) {
            float a = eps[r * 132 + k];
#pragma unroll
            for (int j = 0; j < 5; ++j) z[j] += a * sWo[k * NCLASS + cg * 5 + j];
        }
        float m = z[0];
#pragma unroll
        for (int j = 1; j < 5; ++j) m = fmaxf(m, z[j]);
        for (int off = 1; off < 8; off <<= 1) m = fmaxf(m, __shfl_xor(m, off));
        float s = 0.f;
#pragma unroll
        for (int j = 0; j < 5; ++j) s += expf(z[j] - m);
        for (int off = 1; off < 8; off <<= 1) s += __shfl_xor(s, off);
        float lse = m + logf(s);
        int row = row0 + half * 32 + r;
        if (row < M) {
#pragma unroll
            for (int j = 0; j < 5; ++j) out[(size_t)row * NCLASS + cg * 5 + j] = z[j] - lse;
        }
        __syncthreads();
    }
}

// ===========================================================================
extern "C" void kernel_launch(void* const* d_in, const int* in_sizes, int n_in,
                              void* d_out, int out_size, void* d_ws, size_t ws_size,
                              hipStream_t stream) {
    const float* x      = (const float*)d_in[0];
    const int*   esrc   = (const int*)d_in[1];
    const int*   edst   = (const int*)d_in[2];
    const float* W_in   = (const float*)d_in[3];
    const float* b_in   = (const float*)d_in[4];
    const float* W_mlps = (const float*)d_in[5];
    const float* b_mlps = (const float*)d_in[6];
    const float* W_out  = (const float*)d_in[7];
    const float* b_out  = (const float*)d_in[8];
    float* out = (float*)d_out;

    int N = in_sizes[0] / NFEAT;  // 50000
    int E = in_sizes[1];          // 800000
    int nbuck = (N + 255) >> 8;   // 196

    // workspace carve (~81 MB)
    char* ws = (char*)d_ws;
    size_t hb = (((size_t)N * NHID * sizeof(__bf16)) + 255) & ~(size_t)255;  // 12.8MB
    __bf16* h_hi_a = (__bf16*)ws;
    __bf16* h_lo_a = (__bf16*)(ws + hb);
    __bf16* h_hi_b = (__bf16*)(ws + 2 * hb);
    __bf16* h_lo_b = (__bf16*)(ws + 3 * hb);
    __bf16* sum_hi = (__bf16*)(ws + 4 * hb);
    __bf16* sum_lo = (__bf16*)(ws + 5 * hb);
    // bdata aliases sum_hi's slot: used only during CSR build
    unsigned int* bdata = (unsigned int*)(ws + 4 * hb);
    char* ip = ws + 6 * hb;
    int* row_ptr = (int*)ip;  ip += (((size_t)(N + 1) * 4) + 255) & ~(size_t)255;
    int* srcs    = (int*)ip;  ip += (((size_t)E * 4) + 255) & ~(size_t)255;
    int* bucket_counts = (int*)ip;  ip += 1024;
    int* bucket_start  = (int*)ip;  ip += 1024;
    int* bucket_cursor = (int*)ip;  ip += 1024;
    __bf16* Wt_in_hi   = (__bf16*)ip;  ip += 128 * NFEAT * 2;
    __bf16* Wt_in_lo   = (__bf16*)ip;  ip += 128 * NFEAT * 2;
    __bf16* Wt_mlps_hi = (__bf16*)ip;  ip += 3 * 128 * NHID * 2;
    __bf16* Wt_mlps_lo = (__bf16*)ip;  ip += 3 * 128 * NHID * 2;

    int eb4 = (E + 4095) / 4096;

    // ---- CSR build ----
    hipMemsetAsync(bucket_counts, 0, 1024, stream);
    bucket_hist<<<eb4, 256, 0, stream>>>(edst, bucket_counts, E, nbuck);
    bucket_scan<<<1, 256, 0, stream>>>(bucket_counts, bucket_start, bucket_cursor,
                                       row_ptr, nbuck, E, N);
    bucket_scatter<<<eb4, 256, 0, stream>>>(esrc, edst, bucket_cursor, bdata, E, nbuck);
    bucket_finalize<<<nbuck, 256, 0, stream>>>(bdata, bucket_start, row_ptr, srcs, N);

    // ---- weight prep ----
    transpose_split_all<<<(128 * NFEAT + 3 * 128 * NHID + 255) / 256, 256, 0, stream>>>(
        W_in, W_mlps, Wt_in_hi, Wt_in_lo, Wt_mlps_hi, Wt_mlps_lo);

    int gb = (N + 63) / 64;
    // ---- input layer ----
    gemm_direct<0, NFEAT><<<gb, 256, 0, stream>>>(
        x, (const __bf16*)nullptr, (const __bf16*)nullptr,
        Wt_in_hi, Wt_in_lo, b_in, h_hi_a, h_lo_a, N);

    // ---- GIN layers 0,1 ----
    __bf16* cur_hi = h_hi_a; __bf16* cur_lo = h_lo_a;
    __bf16* nxt_hi = h_hi_b; __bf16* nxt_lo = h_lo_b;
    for (int i = 0; i < 2; ++i) {
        aggregate_fused<<<(N + 3) / 4, 256, 0, stream>>>(cur_hi, cur_lo, row_ptr, srcs,
                                                         sum_hi, sum_lo, N);
        gemm_direct<1, NHID><<<gb, 256, 0, stream>>>(
            (const float*)nullptr, sum_hi, sum_lo,
            Wt_mlps_hi + (size_t)i * 128 * NHID, Wt_mlps_lo + (size_t)i * 128 * NHID,
            b_mlps + (size_t)i * NHID, nxt_hi, nxt_lo, N);
        __bf16* t;
        t = cur_hi; cur_hi = nxt_hi; nxt_hi = t;
        t = cur_lo; cur_lo = nxt_lo; nxt_lo = t;
    }

    // ---- GIN layer 2 fused with output layer + log_softmax ----
    aggregate_fused<<<(N + 3) / 4, 256, 0, stream>>>(cur_hi, cur_lo, row_ptr, srcs,
                                                     sum_hi, sum_lo, N);
    gemm_out_direct<<<gb, 256, 0, stream>>>(sum_hi, sum_lo,
                                            Wt_mlps_hi + (size_t)2 * 128 * NHID,
                                            Wt_mlps_lo + (size_t)2 * 128 * NHID,
                                            b_mlps + (size_t)2 * NHID,
                                            W_out, b_out, out, N);
}

// Round 10
// 322.833 us; speedup vs baseline: 1.3443x; 1.3443x over previous
//
#include <hip/hip_runtime.h>
#include <math.h>

#define NHID 128
#define NFEAT 256
#define NCLASS 40

typedef __bf16 bf16x8 __attribute__((ext_vector_type(8)));
typedef __bf16 bf16x4 __attribute__((ext_vector_type(4)));
typedef float floatx4 __attribute__((ext_vector_type(4)));

// ===========================================================================
// CSR build via 2-level bucketed counting sort (r5-verified).
// Bucket = dst >> 8; record = (dst&255)<<16 | src  (N <= 65536).
// ===========================================================================

__global__ __launch_bounds__(256) void bucket_hist(const int* __restrict__ edst,
                                                   int* __restrict__ bucket_counts,
                                                   int E, int nbuck) {
    __shared__ int lh[256];
    int tid = threadIdx.x;
    lh[tid] = 0;
    __syncthreads();
    int base = blockIdx.x * 4096;
#pragma unroll
    for (int k = 0; k < 16; ++k) {
        int e = base + k * 256 + tid;
        if (e < E) atomicAdd(&lh[edst[e] >> 8], 1);
    }
    __syncthreads();
    if (tid < nbuck && lh[tid]) atomicAdd(&bucket_counts[tid], lh[tid]);
}

__global__ __launch_bounds__(256) void bucket_scan(const int* __restrict__ counts,
                                                   int* __restrict__ start,
                                                   int* __restrict__ cursor,
                                                   int* __restrict__ row_ptr,
                                                   int nbuck, int E, int N) {
    __shared__ int lds[256];
    int tid = threadIdx.x;
    int v = (tid < nbuck) ? counts[tid] : 0;
    lds[tid] = v;
    __syncthreads();
    for (int off = 1; off < 256; off <<= 1) {
        int t = (tid >= off) ? lds[tid - off] : 0;
        __syncthreads();
        lds[tid] += t;
        __syncthreads();
    }
    int excl = lds[tid] - v;
    if (tid < nbuck) { start[tid] = excl; cursor[tid] = excl; }
    if (tid == 0) { start[nbuck] = E; row_ptr[N] = E; }
}

__global__ __launch_bounds__(256) void bucket_scatter(const int* __restrict__ esrc,
                                                      const int* __restrict__ edst,
                                                      int* __restrict__ cursor,
                                                      unsigned int* __restrict__ bdata,
                                                      int E, int nbuck) {
    __shared__ int lh[256];
    __shared__ int lbase[256];
    int tid = threadIdx.x;
    lh[tid] = 0;
    __syncthreads();
    int base = blockIdx.x * 4096;
    unsigned int recs[16];
    short bks[16];
    short lofs[16];
#pragma unroll
    for (int k = 0; k < 16; ++k) {
        int e = base + k * 256 + tid;
        bks[k] = -1;
        if (e < E) {
            int d = edst[e];
            int s = esrc[e];
            int b = d >> 8;
            recs[k] = ((unsigned int)(d & 255) << 16) | (unsigned int)s;
            bks[k] = (short)b;
            lofs[k] = (short)atomicAdd(&lh[b], 1);
        }
    }
    __syncthreads();
    if (tid < nbuck && lh[tid]) lbase[tid] = atomicAdd(&cursor[tid], lh[tid]);
    __syncthreads();
#pragma unroll
    for (int k = 0; k < 16; ++k) {
        if (bks[k] >= 0) bdata[lbase[bks[k]] + lofs[k]] = recs[k];
    }
}

__global__ __launch_bounds__(256) void bucket_finalize(const unsigned int* __restrict__ bdata,
                                                       const int* __restrict__ start,
                                                       int* __restrict__ row_ptr,
                                                       int* __restrict__ srcs,
                                                       int N) {
    __shared__ int hist[256];
    __shared__ int cur[256];
    int b = blockIdx.x;
    int tid = threadIdx.x;
    int s0 = start[b];
    int cnt = start[b + 1] - s0;
    hist[tid] = 0;
    __syncthreads();
    for (int i = tid; i < cnt; i += 256) atomicAdd(&hist[bdata[s0 + i] >> 16], 1);
    __syncthreads();
    int v0 = hist[tid];
    __syncthreads();
    for (int off = 1; off < 256; off <<= 1) {
        int t = (tid >= off) ? hist[tid - off] : 0;
        __syncthreads();
        hist[tid] += t;
        __syncthreads();
    }
    int excl = hist[tid] - v0;
    cur[tid] = excl;
    int node = b * 256 + tid;
    if (node < N) row_ptr[node] = s0 + excl;
    __syncthreads();
    for (int i = tid; i < cnt; i += 256) {
        unsigned int r = bdata[s0 + i];
        int p = atomicAdd(&cur[r >> 16], 1);
        srcs[s0 + p] = (int)(r & 0xffffu);
    }
}

// ===========================================================================
// Weight prep (single dispatch): transpose + split fp32 W[K][128] ->
// Wt_hi/lo[128][K] bf16, for W_in (K=256) and the 3 W_mlps (K=128).
// ===========================================================================
__global__ __launch_bounds__(256) void transpose_split_all(
    const float* __restrict__ Win, const float* __restrict__ Wmlps,
    __bf16* __restrict__ dInHi, __bf16* __restrict__ dInLo,
    __bf16* __restrict__ dMlHi, __bf16* __restrict__ dMlLo) {
    const int TOT_IN = 128 * NFEAT;      // 32768
    const int TOT_ML = 3 * 128 * NHID;   // 49152
    int i = blockIdx.x * 256 + threadIdx.x;
    if (i < TOT_IN) {
        int n = i / NFEAT;
        int k = i - n * NFEAT;
        float v = Win[(size_t)k * 128 + n];
        __bf16 h = (__bf16)v;
        dInHi[i] = h;
        dInLo[i] = (__bf16)(v - (float)h);
    } else if (i < TOT_IN + TOT_ML) {
        int r = i - TOT_IN;
        int per = 128 * NHID;
        int l = r / per;
        int rr = r - l * per;
        int n = rr / NHID;
        int k = rr - n * NHID;
        float v = Wmlps[(size_t)l * per + (size_t)k * 128 + n];
        __bf16 h = (__bf16)v;
        dMlHi[r] = h;
        dMlLo[r] = (__bf16)(v - (float)h);
    }
}

// ===========================================================================
// Fused aggregate (r5-verified): sum = h[node](hi+lo) + sum_{src} h_hi[src].
// One wave/node; 16 lanes x 16B row; 16 edges (4 gathers) in flight.
// ===========================================================================
__global__ __launch_bounds__(256) void aggregate_fused(const __bf16* __restrict__ hhi,
                                                       const __bf16* __restrict__ hlo,
                                                       const int* __restrict__ row_ptr,
                                                       const int* __restrict__ srcs,
                                                       __bf16* __restrict__ ohi,
                                                       __bf16* __restrict__ olo, int N) {
    int tid = threadIdx.x;
    int node = blockIdx.x * 4 + (tid >> 6);
    if (node >= N) return;
    int lane = tid & 63;
    int g = lane >> 4;
    int c = lane & 15;
    int beg = row_ptr[node];
    int end = row_ptr[node + 1];
    const bf16x8* hv = (const bf16x8*)hhi;

    bf16x8 sh = hv[(size_t)node * 16 + c];
    bf16x8 sl = ((const bf16x8*)hlo)[(size_t)node * 16 + c];

    float a[8], b2[8];
#pragma unroll
    for (int j = 0; j < 8; ++j) { a[j] = 0.f; b2[j] = 0.f; }

    int i = beg;
    for (; i + 16 <= end; i += 16) {
        int s0 = __builtin_nontemporal_load(&srcs[i + g]);
        int s1 = __builtin_nontemporal_load(&srcs[i + 4 + g]);
        int s2 = __builtin_nontemporal_load(&srcs[i + 8 + g]);
        int s3 = __builtin_nontemporal_load(&srcs[i + 12 + g]);
        bf16x8 v0 = hv[(size_t)s0 * 16 + c];
        bf16x8 v1 = hv[(size_t)s1 * 16 + c];
        bf16x8 v2 = hv[(size_t)s2 * 16 + c];
        bf16x8 v3 = hv[(size_t)s3 * 16 + c];
#pragma unroll
        for (int j = 0; j < 8; ++j) {
            a[j] += (float)v0[j] + (float)v2[j];
            b2[j] += (float)v1[j] + (float)v3[j];
        }
    }
    for (; i + 8 <= end; i += 8) {
        int s0 = __builtin_nontemporal_load(&srcs[i + g]);
        int s1 = __builtin_nontemporal_load(&srcs[i + 4 + g]);
        bf16x8 v0 = hv[(size_t)s0 * 16 + c];
        bf16x8 v1 = hv[(size_t)s1 * 16 + c];
#pragma unroll
        for (int j = 0; j < 8; ++j) { a[j] += (float)v0[j]; b2[j] += (float)v1[j]; }
    }
    for (; i < end; i += 4) {
        if (i + g < end) {
            int s = __builtin_nontemporal_load(&srcs[i + g]);
            bf16x8 v = hv[(size_t)s * 16 + c];
#pragma unroll
            for (int j = 0; j < 8; ++j) a[j] += (float)v[j];
        }
    }
#pragma unroll
    for (int j = 0; j < 8; ++j) a[j] += b2[j];
#pragma unroll
    for (int j = 0; j < 8; ++j) a[j] += __shfl_xor(a[j], 16);
#pragma unroll
    for (int j = 0; j < 8; ++j) a[j] += __shfl_xor(a[j], 32);

    if (g == 0) {
        bf16x8 whi, wlo;
#pragma unroll
        for (int j = 0; j < 8; ++j) {
            float v = a[j] + (float)sh[j] + (float)sl[j];
            __bf16 h = (__bf16)v;
            whi[j] = h;
            wlo[j] = (__bf16)(v - (float)h);
        }
        ((bf16x8*)ohi)[(size_t)node * 16 + c] = whi;
        ((bf16x8*)olo)[(size_t)node * 16 + c] = wlo;
    }
}

// ===========================================================================
// Input-layer GEMM (r5-verified, MODE 0): h0 = relu(x @ W_in + b_in), K=256.
// Tile 64x128, BK=64, XOR-swizzled LDS, triple MFMA.
// ===========================================================================
__global__ __launch_bounds__(256) void gemm_in(
    const float* __restrict__ Af,
    const __bf16* __restrict__ Wthi, const __bf16* __restrict__ Wtlo,
    const float* __restrict__ bias, __bf16* __restrict__ Ohi,
    __bf16* __restrict__ Olo, int M, int K) {
    __shared__ __align__(16) char smem[49152];
    __bf16* sAhi = (__bf16*)smem;
    __bf16* sAlo = (__bf16*)(smem + 8192);
    __bf16* sWhi = (__bf16*)(smem + 16384);
    __bf16* sWlo = (__bf16*)(smem + 32768);

    int tid = threadIdx.x;
    int row0 = blockIdx.x * 64;
    int wave = tid >> 6;
    int l = tid & 63;
    int m16 = l & 15;
    int q = l >> 4;
    int axor = m16 & 7;
    int arow = wave * 16 + m16;

    floatx4 acc[8];
#pragma unroll
    for (int t = 0; t < 8; ++t) acc[t] = (floatx4){0.f, 0.f, 0.f, 0.f};

    for (int k0 = 0; k0 < K; k0 += 64) {
#pragma unroll
        for (int it = 0; it < 2; ++it) {
            int lin = it * 2048 + tid * 8;
            int row = lin >> 6, k = lin & 63;
            int g = min(row0 + row, M - 1);
            int off = row * 64 + (((k >> 3) ^ (row & 7)) << 3);
            float4 v0 = *(const float4*)&Af[(size_t)g * K + k0 + k];
            float4 v1 = *(const float4*)&Af[(size_t)g * K + k0 + k + 4];
            float s[8] = {v0.x, v0.y, v0.z, v0.w, v1.x, v1.y, v1.z, v1.w};
            bf16x8 shi, slo;
#pragma unroll
            for (int j = 0; j < 8; ++j) {
                __bf16 h = (__bf16)s[j];
                shi[j] = h;
                slo[j] = (__bf16)(s[j] - (float)h);
            }
            *(bf16x8*)(sAhi + off) = shi;
            *(bf16x8*)(sAlo + off) = slo;
        }
#pragma unroll
        for (int it = 0; it < 4; ++it) {
            int lin = it * 2048 + tid * 8;
            int n = lin >> 6, kk = lin & 63;
            int off = n * 64 + (((kk >> 3) ^ (n & 7)) << 3);
            *(bf16x8*)(sWhi + off) = *(const bf16x8*)&Wthi[(size_t)n * K + k0 + kk];
            *(bf16x8*)(sWlo + off) = *(const bf16x8*)&Wtlo[(size_t)n * K + k0 + kk];
        }
        __syncthreads();

#pragma unroll
        for (int s = 0; s < 2; ++s) {
            int sw = (((s * 4 + q) ^ axor) << 3);
            bf16x8 ahi = *(bf16x8*)(sAhi + arow * 64 + sw);
            bf16x8 alo = *(bf16x8*)(sAlo + arow * 64 + sw);
#pragma unroll
            for (int t = 0; t < 8; ++t) {
                int n = t * 16 + m16;
                bf16x8 bhi = *(bf16x8*)(sWhi + n * 64 + sw);
                bf16x8 blo = *(bf16x8*)(sWlo + n * 64 + sw);
                acc[t] = __builtin_amdgcn_mfma_f32_16x16x32_bf16(ahi, bhi, acc[t], 0, 0, 0);
                acc[t] = __builtin_amdgcn_mfma_f32_16x16x32_bf16(alo, bhi, acc[t], 0, 0, 0);
                acc[t] = __builtin_amdgcn_mfma_f32_16x16x32_bf16(ahi, blo, acc[t], 0, 0, 0);
            }
        }
        __syncthreads();
    }

    float* eps = (float*)(smem + 16384);
#pragma unroll
    for (int t = 0; t < 8; ++t) {
        int col = t * 16 + m16;
        float bb = bias[col];
#pragma unroll
        for (int i = 0; i < 4; ++i) {
            int row = wave * 16 + q * 4 + i;
            eps[row * 128 + col] = fmaxf(acc[t][i] + bb, 0.f);
        }
    }
    __syncthreads();
#pragma unroll
    for (int it = 0; it < 8; ++it) {
        int lin = it * 1024 + tid * 4;
        int row = lin >> 7, col = lin & 127;
        int g = row0 + row;
        if (g < M) {
            float4 v = *(float4*)(eps + lin);
            bf16x4 hi, lo;
            float vv[4] = {v.x, v.y, v.z, v.w};
#pragma unroll
            for (int j = 0; j < 4; ++j) {
                __bf16 h = (__bf16)vv[j];
                hi[j] = h;
                lo[j] = (__bf16)(vv[j] - (float)h);
            }
            *(bf16x4*)&Ohi[(size_t)g * 128 + col] = hi;
            *(bf16x4*)&Olo[(size_t)g * 128 + col] = lo;
        }
    }
}

// ===========================================================================
// NEW: mid-layer GEMM, 64 rows x 64 cols, K=128, stage-W-ONCE + barrier-free
// k-loop. W tile (64 cols x 128 k, hi+lo) = 32KB staged a single time ->
// 5 blocks/CU; k-loop is pure {A direct-load + swizzled ds_read + MFMA} with
// zero barriers. A fragments read direct from global (16 rows x 64B segments,
// L2/L3-served, 8 loads/wave). Epilogue reuses W LDS (barrier-guarded).
// Grid: 2 col-blocks per 64-row block (blockIdx.x = rowblk*2 + colhalf).
// ===========================================================================
__global__ __launch_bounds__(256) void gemm64(
    const __bf16* __restrict__ Ahi, const __bf16* __restrict__ Alo,
    const __bf16* __restrict__ Wthi, const __bf16* __restrict__ Wtlo,
    const float* __restrict__ bias, __bf16* __restrict__ Ohi,
    __bf16* __restrict__ Olo, int M) {
    __shared__ __align__(16) char smem[32768];
    __bf16* sWhi = (__bf16*)smem;                // 64x128 = 16KB
    __bf16* sWlo = (__bf16*)(smem + 16384);      // 16KB

    int tid = threadIdx.x;
    int row0 = (blockIdx.x >> 1) * 64;
    int n0 = (blockIdx.x & 1) * 64;
    int wave = tid >> 6;
    int l = tid & 63;
    int m16 = l & 15;
    int q = l >> 4;
    int garow = min(row0 + wave * 16 + m16, M - 1);

    // ---- stage W once (32KB, coalesced 16B/lane) ----
#pragma unroll
    for (int it = 0; it < 4; ++it) {
        int lin = it * 2048 + tid * 8;
        int row = lin >> 7, k = lin & 127;
        int off = row * 128 + (((k >> 3) ^ (row & 7)) << 3);
        *(bf16x8*)(sWhi + off) = *(const bf16x8*)&Wthi[(size_t)(n0 + row) * 128 + k];
        *(bf16x8*)(sWlo + off) = *(const bf16x8*)&Wtlo[(size_t)(n0 + row) * 128 + k];
    }
    __syncthreads();

    floatx4 acc[4];
#pragma unroll
    for (int t = 0; t < 4; ++t) acc[t] = (floatx4){0.f, 0.f, 0.f, 0.f};

    // ---- barrier-free k-loop: 4 fragment-steps of 32 k each ----
#pragma unroll
    for (int fs = 0; fs < 4; ++fs) {
        int kk = fs * 32 + q * 8;
        bf16x8 ahi = *(const bf16x8*)&Ahi[(size_t)garow * 128 + kk];
        bf16x8 alo = *(const bf16x8*)&Alo[(size_t)garow * 128 + kk];
#pragma unroll
        for (int t = 0; t < 4; ++t) {
            int n = t * 16 + m16;
            int soff = n * 128 + (((kk >> 3) ^ (n & 7)) << 3);
            bf16x8 bhi = *(bf16x8*)(sWhi + soff);
            bf16x8 blo = *(bf16x8*)(sWlo + soff);
            acc[t] = __builtin_amdgcn_mfma_f32_16x16x32_bf16(ahi, bhi, acc[t], 0, 0, 0);
            acc[t] = __builtin_amdgcn_mfma_f32_16x16x32_bf16(alo, bhi, acc[t], 0, 0, 0);
            acc[t] = __builtin_amdgcn_mfma_f32_16x16x32_bf16(ahi, blo, acc[t], 0, 0, 0);
        }
    }

    // ---- epilogue: reuse W LDS as 64x68 fp32 buffer ----
    __syncthreads();  // all waves done reading W
    float* eps = (float*)smem;  // 64*68*4 = 17408B
#pragma unroll
    for (int t = 0; t < 4; ++t) {
        float bb = bias[n0 + t * 16 + m16];
#pragma unroll
        for (int i = 0; i < 4; ++i) {
            int row = wave * 16 + q * 4 + i;
            eps[row * 68 + t * 16 + m16] = fmaxf(acc[t][i] + bb, 0.f);
        }
    }
    __syncthreads();
#pragma unroll
    for (int it = 0; it < 4; ++it) {
        int lin = it * 1024 + tid * 4;
        int row = lin >> 6, col = lin & 63;
        int g = row0 + row;
        if (g < M) {
            float4 v = *(float4*)(eps + row * 68 + col);
            bf16x4 hi, lo;
            float vv[4] = {v.x, v.y, v.z, v.w};
#pragma unroll
            for (int j = 0; j < 4; ++j) {
                __bf16 h = (__bf16)vv[j];
                hi[j] = h;
                lo[j] = (__bf16)(vv[j] - (float)h);
            }
            *(bf16x4*)&Ohi[(size_t)g * 128 + n0 + col] = hi;
            *(bf16x4*)&Olo[(size_t)g * 128 + n0 + col] = lo;
        }
    }
}

// ===========================================================================
// Final GIN-layer GEMM fused with output layer + log_softmax (r5-verified).
// ===========================================================================
__global__ __launch_bounds__(256) void gemm_out(
    const __bf16* __restrict__ Ahi, const __bf16* __restrict__ Alo,
    const __bf16* __restrict__ Wthi, const __bf16* __restrict__ Wtlo,
    const float* __restrict__ bias,
    const float* __restrict__ Wout, const float* __restrict__ bout,
    float* __restrict__ out, int M) {
    __shared__ __align__(16) char smem[57344];
    __bf16* sAhi = (__bf16*)smem;
    __bf16* sAlo = (__bf16*)(smem + 8192);
    __bf16* sWhi = (__bf16*)(smem + 16384);
    __bf16* sWlo = (__bf16*)(smem + 32768);

    int tid = threadIdx.x;
    int row0 = blockIdx.x * 64;
    int wave = tid >> 6;
    int l = tid & 63;
    int m16 = l & 15;
    int q = l >> 4;
    int axor = m16 & 7;
    int arow = wave * 16 + m16;

    floatx4 acc[8];
#pragma unroll
    for (int t = 0; t < 8; ++t) acc[t] = (floatx4){0.f, 0.f, 0.f, 0.f};

    for (int k0 = 0; k0 < 128; k0 += 64) {
#pragma unroll
        for (int it = 0; it < 2; ++it) {
            int lin = it * 2048 + tid * 8;
            int row = lin >> 6, k = lin & 63;
            int g = min(row0 + row, M - 1);
            int off = row * 64 + (((k >> 3) ^ (row & 7)) << 3);
            *(bf16x8*)(sAhi + off) = *(const bf16x8*)&Ahi[(size_t)g * 128 + k0 + k];
            *(bf16x8*)(sAlo + off) = *(const bf16x8*)&Alo[(size_t)g * 128 + k0 + k];
        }
#pragma unroll
        for (int it = 0; it < 4; ++it) {
            int lin = it * 2048 + tid * 8;
            int n = lin >> 6, kk = lin & 63;
            int off = n * 64 + (((kk >> 3) ^ (n & 7)) << 3);
            *(bf16x8*)(sWhi + off) = *(const bf16x8*)&Wthi[(size_t)n * 128 + k0 + kk];
            *(bf16x8*)(sWlo + off) = *(const bf16x8*)&Wtlo[(size_t)n * 128 + k0 + kk];
        }
        __syncthreads();

#pragma unroll
        for (int s = 0; s < 2; ++s) {
            int sw = (((s * 4 + q) ^ axor) << 3);
            bf16x8 ahi = *(bf16x8*)(sAhi + arow * 64 + sw);
            bf16x8 alo = *(bf16x8*)(sAlo + arow * 64 + sw);
#pragma unroll
            for (int t = 0; t < 8; ++t) {
                int n = t * 16 + m16;
                bf16x8 bhi = *(bf16x8*)(sWhi + n * 64 + sw);
                bf16x8 blo = *(bf16x8*)(sWlo + n * 64 + sw);
                acc[t] = __builtin_amdgcn_mfma_f32_16x16x32_bf16(ahi, bhi, acc[t], 0, 0, 0);
                acc[t] = __builtin_amdgcn_mfma_f32_16x16x32_bf16(alo, bhi, acc[t], 0, 0, 0);
                acc[t] = __builtin_amdgcn_mfma_f32_16x16x32_bf16(ahi, blo, acc[t], 0, 0, 0);
            }
        }
        __syncthreads();
    }

    float* eps = (float*)smem;                    // 64*132*4 = 33792 B
    float* sWo = (float*)(smem + 34816);          // 128*40*4 = 20480 B
    float* sb  = (float*)(smem + 55296);          // 160 B
#pragma unroll
    for (int t = 0; t < 8; ++t) {
        int col = t * 16 + m16;
        float bb = bias[col];
#pragma unroll
        for (int i = 0; i < 4; ++i) {
            int row = wave * 16 + q * 4 + i;
            eps[row * 132 + col] = fmaxf(acc[t][i] + bb, 0.f);
        }
    }
    for (int i = tid; i < 128 * NCLASS; i += 256) sWo[i] = Wout[i];
    if (tid < NCLASS) sb[tid] = bout[tid];
    __syncthreads();

    int r = tid >> 2;
    int cg = tid & 3;
    float z[10];
#pragma unroll
    for (int j = 0; j < 10; ++j) z[j] = sb[cg * 10 + j];
    for (int k = 0; k < 128; ++k) {
        float a = eps[r * 132 + k];
#pragma unroll
        for (int j = 0; j < 10; ++j) z[j] += a * sWo[k * NCLASS + cg * 10 + j];
    }
    float m = z[0];
#pragma unroll
    for (int j = 1; j < 10; ++j) m = fmaxf(m, z[j]);
    m = fmaxf(m, __shfl_xor(m, 1));
    m = fmaxf(m, __shfl_xor(m, 2));
    float s = 0.f;
#pragma unroll
    for (int j = 0; j < 10; ++j) s += expf(z[j] - m);
    s += __shfl_xor(s, 1);
    s += __shfl_xor(s, 2);
    float lse = m + logf(s);
    int row = row0 + r;
    if (row < M) {
#pragma unroll
        for (int j = 0; j < 10; ++j) out[(size_t)row * NCLASS + cg * 10 + j] = z[j] - lse;
    }
}

// ===========================================================================
extern "C" void kernel_launch(void* const* d_in, const int* in_sizes, int n_in,
                              void* d_out, int out_size, void* d_ws, size_t ws_size,
                              hipStream_t stream) {
    const float* x      = (const float*)d_in[0];
    const int*   esrc   = (const int*)d_in[1];
    const int*   edst   = (const int*)d_in[2];
    const float* W_in   = (const float*)d_in[3];
    const float* b_in   = (const float*)d_in[4];
    const float* W_mlps = (const float*)d_in[5];
    const float* b_mlps = (const float*)d_in[6];
    const float* W_out  = (const float*)d_in[7];
    const float* b_out  = (const float*)d_in[8];
    float* out = (float*)d_out;

    int N = in_sizes[0] / NFEAT;  // 50000
    int E = in_sizes[1];          // 800000
    int nbuck = (N + 255) >> 8;   // 196

    // workspace carve (~81 MB)
    char* ws = (char*)d_ws;
    size_t hb = (((size_t)N * NHID * sizeof(__bf16)) + 255) & ~(size_t)255;  // 12.8MB
    __bf16* h_hi_a = (__bf16*)ws;
    __bf16* h_lo_a = (__bf16*)(ws + hb);
    __bf16* h_hi_b = (__bf16*)(ws + 2 * hb);
    __bf16* h_lo_b = (__bf16*)(ws + 3 * hb);
    __bf16* sum_hi = (__bf16*)(ws + 4 * hb);
    __bf16* sum_lo = (__bf16*)(ws + 5 * hb);
    // bdata aliases sum_hi's slot: used only during CSR build
    unsigned int* bdata = (unsigned int*)(ws + 4 * hb);
    char* ip = ws + 6 * hb;
    int* row_ptr = (int*)ip;  ip += (((size_t)(N + 1) * 4) + 255) & ~(size_t)255;
    int* srcs    = (int*)ip;  ip += (((size_t)E * 4) + 255) & ~(size_t)255;
    int* bucket_counts = (int*)ip;  ip += 1024;
    int* bucket_start  = (int*)ip;  ip += 1024;
    int* bucket_cursor = (int*)ip;  ip += 1024;
    __bf16* Wt_in_hi   = (__bf16*)ip;  ip += 128 * NFEAT * 2;
    __bf16* Wt_in_lo   = (__bf16*)ip;  ip += 128 * NFEAT * 2;
    __bf16* Wt_mlps_hi = (__bf16*)ip;  ip += 3 * 128 * NHID * 2;
    __bf16* Wt_mlps_lo = (__bf16*)ip;  ip += 3 * 128 * NHID * 2;

    int eb4 = (E + 4095) / 4096;

    // ---- CSR build ----
    hipMemsetAsync(bucket_counts, 0, 1024, stream);
    bucket_hist<<<eb4, 256, 0, stream>>>(edst, bucket_counts, E, nbuck);
    bucket_scan<<<1, 256, 0, stream>>>(bucket_counts, bucket_start, bucket_cursor,
                                       row_ptr, nbuck, E, N);
    bucket_scatter<<<eb4, 256, 0, stream>>>(esrc, edst, bucket_cursor, bdata, E, nbuck);
    bucket_finalize<<<nbuck, 256, 0, stream>>>(bdata, bucket_start, row_ptr, srcs, N);

    // ---- weight prep ----
    transpose_split_all<<<(128 * NFEAT + 3 * 128 * NHID + 255) / 256, 256, 0, stream>>>(
        W_in, W_mlps, Wt_in_hi, Wt_in_lo, Wt_mlps_hi, Wt_mlps_lo);

    int gb = (N + 63) / 64;
    // ---- input layer ----
    gemm_in<<<gb, 256, 0, stream>>>(x, Wt_in_hi, Wt_in_lo, b_in, h_hi_a, h_lo_a, N, NFEAT);

    // ---- GIN layers 0,1: aggregate + stage-W-once barrier-free GEMM ----
    __bf16* cur_hi = h_hi_a; __bf16* cur_lo = h_lo_a;
    __bf16* nxt_hi = h_hi_b; __bf16* nxt_lo = h_lo_b;
    for (int i = 0; i < 2; ++i) {
        aggregate_fused<<<(N + 3) / 4, 256, 0, stream>>>(cur_hi, cur_lo, row_ptr, srcs,
                                                         sum_hi, sum_lo, N);
        gemm64<<<gb * 2, 256, 0, stream>>>(
            sum_hi, sum_lo,
            Wt_mlps_hi + (size_t)i * 128 * NHID, Wt_mlps_lo + (size_t)i * 128 * NHID,
            b_mlps + (size_t)i * NHID, nxt_hi, nxt_lo, N);
        __bf16* t;
        t = cur_hi; cur_hi = nxt_hi; nxt_hi = t;
        t = cur_lo; cur_lo = nxt_lo; nxt_lo = t;
    }

    // ---- GIN layer 2 fused with output layer + log_softmax ----
    aggregate_fused<<<(N + 3) / 4, 256, 0, stream>>>(cur_hi, cur_lo, row_ptr, srcs,
                                                     sum_hi, sum_lo, N);
    gemm_out<<<gb, 256, 0, stream>>>(sum_hi, sum_lo,
                                     Wt_mlps_hi + (size_t)2 * 128 * NHID,
                                     Wt_mlps_lo + (size_t)2 * 128 * NHID,
                                     b_mlps + (size_t)2 * NHID,
                                     W_out, b_out, out, N);
}

// Round 11
// 322.170 us; speedup vs baseline: 1.3471x; 1.0021x over previous
//
#include <hip/hip_runtime.h>
#include <math.h>

#define NHID 128
#define NFEAT 256
#define NCLASS 40

typedef __bf16 bf16x8 __attribute__((ext_vector_type(8)));
typedef __bf16 bf16x4 __attribute__((ext_vector_type(4)));
typedef float floatx4 __attribute__((ext_vector_type(4)));

// ===========================================================================
// CSR build via 2-level bucketed counting sort.
// Bucket = dst >> 8; record = (dst&255)<<16 | src  (N <= 65536).
// Dispatch A: hist (blocks [0,eb4)) || weight transpose (blocks [eb4,eb4+320)).
// ===========================================================================
__global__ __launch_bounds__(256) void hist_transpose(
    const int* __restrict__ edst, int* __restrict__ bucket_counts, int E, int eb4,
    int nbuck,
    const float* __restrict__ Win, const float* __restrict__ Wmlps,
    __bf16* __restrict__ dInHi, __bf16* __restrict__ dInLo,
    __bf16* __restrict__ dMlHi, __bf16* __restrict__ dMlLo) {
    __shared__ int lh[256];
    int tid = threadIdx.x;
    int bid = blockIdx.x;
    if (bid < eb4) {
        lh[tid] = 0;
        __syncthreads();
        int base = bid * 4096;
#pragma unroll
        for (int k = 0; k < 16; ++k) {
            int e = base + k * 256 + tid;
            if (e < E) atomicAdd(&lh[edst[e] >> 8], 1);
        }
        __syncthreads();
        if (tid < nbuck && lh[tid]) atomicAdd(&bucket_counts[tid], lh[tid]);
    } else {
        const int TOT_IN = 128 * NFEAT;      // 32768
        const int TOT_ML = 3 * 128 * NHID;   // 49152
        int i = (bid - eb4) * 256 + tid;
        if (i < TOT_IN) {
            int n = i / NFEAT;
            int k = i - n * NFEAT;
            float v = Win[(size_t)k * 128 + n];
            __bf16 h = (__bf16)v;
            dInHi[i] = h;
            dInLo[i] = (__bf16)(v - (float)h);
        } else if (i < TOT_IN + TOT_ML) {
            int r = i - TOT_IN;
            int per = 128 * NHID;
            int l = r / per;
            int rr = r - l * per;
            int n = rr / NHID;
            int k = rr - n * NHID;
            float v = Wmlps[(size_t)l * per + (size_t)k * 128 + n];
            __bf16 h = (__bf16)v;
            dMlHi[r] = h;
            dMlLo[r] = (__bf16)(v - (float)h);
        }
    }
}

__global__ __launch_bounds__(256) void bucket_scan(const int* __restrict__ counts,
                                                   int* __restrict__ start,
                                                   int* __restrict__ cursor,
                                                   int* __restrict__ row_ptr,
                                                   int nbuck, int E, int N) {
    __shared__ int lds[256];
    int tid = threadIdx.x;
    int v = (tid < nbuck) ? counts[tid] : 0;
    lds[tid] = v;
    __syncthreads();
    for (int off = 1; off < 256; off <<= 1) {
        int t = (tid >= off) ? lds[tid - off] : 0;
        __syncthreads();
        lds[tid] += t;
        __syncthreads();
    }
    int excl = lds[tid] - v;
    if (tid < nbuck) { start[tid] = excl; cursor[tid] = excl; }
    if (tid == 0) { start[nbuck] = E; row_ptr[N] = E; }
}

__global__ __launch_bounds__(256) void bucket_scatter(const int* __restrict__ esrc,
                                                      const int* __restrict__ edst,
                                                      int* __restrict__ cursor,
                                                      unsigned int* __restrict__ bdata,
                                                      int E, int nbuck) {
    __shared__ int lh[256];
    __shared__ int lbase[256];
    int tid = threadIdx.x;
    lh[tid] = 0;
    __syncthreads();
    int base = blockIdx.x * 4096;
    unsigned int recs[16];
    short bks[16];
    short lofs[16];
#pragma unroll
    for (int k = 0; k < 16; ++k) {
        int e = base + k * 256 + tid;
        bks[k] = -1;
        if (e < E) {
            int d = edst[e];
            int s = esrc[e];
            int b = d >> 8;
            recs[k] = ((unsigned int)(d & 255) << 16) | (unsigned int)s;
            bks[k] = (short)b;
            lofs[k] = (short)atomicAdd(&lh[b], 1);
        }
    }
    __syncthreads();
    if (tid < nbuck && lh[tid]) lbase[tid] = atomicAdd(&cursor[tid], lh[tid]);
    __syncthreads();
#pragma unroll
    for (int k = 0; k < 16; ++k) {
        if (bks[k] >= 0) bdata[lbase[bks[k]] + lofs[k]] = recs[k];
    }
}

// ===========================================================================
// Dispatch D: FINALIZE (blocks [0,nbuck)) || GEMM_IN (blocks [nbuck,..)).
// Finalize: original r5 counting sort using bucket_start (no phist).
// gemm_in64: stage-W-ONCE barrier-free GEMM, 64 rows x 64 cols, K=256.
//   W tile 64x256 hi/lo = 64KB staged once; k-loop = pure {fp32 A direct-load
//   + hi/lo split + swizzled ds_read + MFMA}, zero barriers. Epilogue reuses
//   the W LDS. blockIdx-nbuck = rowblk*2 + colhalf.
// ===========================================================================
__global__ __launch_bounds__(256) void fin_gemmin64(
    const unsigned int* __restrict__ bdata, const int* __restrict__ start,
    int* __restrict__ row_ptr, int* __restrict__ srcs, int N, int nbuck,
    const float* __restrict__ Af,
    const __bf16* __restrict__ Wthi, const __bf16* __restrict__ Wtlo,
    const float* __restrict__ bias, __bf16* __restrict__ Ohi,
    __bf16* __restrict__ Olo) {
    __shared__ __align__(16) char smem[65536];
    int tid = threadIdx.x;
    if ((int)blockIdx.x < nbuck) {
        int* hist = (int*)smem;
        int* cur  = (int*)(smem + 1024);
        int b = blockIdx.x;
        int s0 = start[b];
        int cnt = start[b + 1] - s0;
        hist[tid] = 0;
        __syncthreads();
        for (int i = tid; i < cnt; i += 256) atomicAdd(&hist[bdata[s0 + i] >> 16], 1);
        __syncthreads();
        int v0 = hist[tid];
        __syncthreads();
        for (int off = 1; off < 256; off <<= 1) {
            int t = (tid >= off) ? hist[tid - off] : 0;
            __syncthreads();
            hist[tid] += t;
            __syncthreads();
        }
        int excl = hist[tid] - v0;
        cur[tid] = excl;
        int node = b * 256 + tid;
        if (node < N) row_ptr[node] = s0 + excl;
        __syncthreads();
        for (int i = tid; i < cnt; i += 256) {
            unsigned int r = bdata[s0 + i];
            int p = atomicAdd(&cur[r >> 16], 1);
            srcs[s0 + p] = (int)(r & 0xffffu);
        }
        return;
    }
    // ---------------- gemm_in64 ----------------
    __bf16* sWhi = (__bf16*)smem;                // 64x256 = 32KB
    __bf16* sWlo = (__bf16*)(smem + 32768);      // 32KB
    int bix = (int)blockIdx.x - nbuck;
    int row0 = (bix >> 1) * 64;
    int n0 = (bix & 1) * 64;
    int wave = tid >> 6;
    int l = tid & 63;
    int m16 = l & 15;
    int q = l >> 4;
    int garow = min(row0 + wave * 16 + m16, N - 1);

    // stage W once (64 cols x 256 k, hi+lo)
#pragma unroll
    for (int it = 0; it < 8; ++it) {
        int lin = it * 2048 + tid * 8;
        int wr = lin >> 8, k = lin & 255;
        int off = wr * 256 + (((k >> 3) ^ (wr & 7)) << 3);
        *(bf16x8*)(sWhi + off) = *(const bf16x8*)&Wthi[(size_t)(n0 + wr) * 256 + k];
        *(bf16x8*)(sWlo + off) = *(const bf16x8*)&Wtlo[(size_t)(n0 + wr) * 256 + k];
    }
    __syncthreads();

    floatx4 acc[4];
#pragma unroll
    for (int t = 0; t < 4; ++t) acc[t] = (floatx4){0.f, 0.f, 0.f, 0.f};

    // barrier-free k-loop: 8 fragment-steps of 32 k
#pragma unroll
    for (int fs = 0; fs < 8; ++fs) {
        int kk = fs * 32 + q * 8;
        float4 v0 = *(const float4*)&Af[(size_t)garow * 256 + kk];
        float4 v1 = *(const float4*)&Af[(size_t)garow * 256 + kk + 4];
        float sv[8] = {v0.x, v0.y, v0.z, v0.w, v1.x, v1.y, v1.z, v1.w};
        bf16x8 ahi, alo;
#pragma unroll
        for (int j = 0; j < 8; ++j) {
            __bf16 h = (__bf16)sv[j];
            ahi[j] = h;
            alo[j] = (__bf16)(sv[j] - (float)h);
        }
#pragma unroll
        for (int t = 0; t < 4; ++t) {
            int n = t * 16 + m16;
            int soff = n * 256 + (((kk >> 3) ^ (n & 7)) << 3);
            bf16x8 bhi = *(bf16x8*)(sWhi + soff);
            bf16x8 blo = *(bf16x8*)(sWlo + soff);
            acc[t] = __builtin_amdgcn_mfma_f32_16x16x32_bf16(ahi, bhi, acc[t], 0, 0, 0);
            acc[t] = __builtin_amdgcn_mfma_f32_16x16x32_bf16(alo, bhi, acc[t], 0, 0, 0);
            acc[t] = __builtin_amdgcn_mfma_f32_16x16x32_bf16(ahi, blo, acc[t], 0, 0, 0);
        }
    }

    // epilogue: reuse W LDS as 64x68 fp32 buffer
    __syncthreads();
    float* eps = (float*)smem;
#pragma unroll
    for (int t = 0; t < 4; ++t) {
        float bb = bias[n0 + t * 16 + m16];
#pragma unroll
        for (int i = 0; i < 4; ++i) {
            int row = wave * 16 + q * 4 + i;
            eps[row * 68 + t * 16 + m16] = fmaxf(acc[t][i] + bb, 0.f);
        }
    }
    __syncthreads();
#pragma unroll
    for (int it = 0; it < 4; ++it) {
        int lin = it * 1024 + tid * 4;
        int row = lin >> 6, col = lin & 63;
        int g = row0 + row;
        if (g < N) {
            float4 v = *(float4*)(eps + row * 68 + col);
            bf16x4 hi, lo;
            float vv[4] = {v.x, v.y, v.z, v.w};
#pragma unroll
            for (int j = 0; j < 4; ++j) {
                __bf16 h = (__bf16)vv[j];
                hi[j] = h;
                lo[j] = (__bf16)(vv[j] - (float)h);
            }
            *(bf16x4*)&Ohi[(size_t)g * 128 + n0 + col] = hi;
            *(bf16x4*)&Olo[(size_t)g * 128 + n0 + col] = lo;
        }
    }
}

// ===========================================================================
// Fused aggregate (r5-verified): sum = h[node](hi+lo) + sum_{src} h_hi[src].
// One wave/node; 16 lanes x 16B row; 16 edges (4 gathers) in flight.
// ===========================================================================
__global__ __launch_bounds__(256) void aggregate_fused(const __bf16* __restrict__ hhi,
                                                       const __bf16* __restrict__ hlo,
                                                       const int* __restrict__ row_ptr,
                                                       const int* __restrict__ srcs,
                                                       __bf16* __restrict__ ohi,
                                                       __bf16* __restrict__ olo, int N) {
    int tid = threadIdx.x;
    int node = blockIdx.x * 4 + (tid >> 6);
    if (node >= N) return;
    int lane = tid & 63;
    int g = lane >> 4;
    int c = lane & 15;
    int beg = row_ptr[node];
    int end = row_ptr[node + 1];
    const bf16x8* hv = (const bf16x8*)hhi;

    bf16x8 sh = hv[(size_t)node * 16 + c];
    bf16x8 sl = ((const bf16x8*)hlo)[(size_t)node * 16 + c];

    float a[8], b2[8];
#pragma unroll
    for (int j = 0; j < 8; ++j) { a[j] = 0.f; b2[j] = 0.f; }

    int i = beg;
    for (; i + 16 <= end; i += 16) {
        int s0 = __builtin_nontemporal_load(&srcs[i + g]);
        int s1 = __builtin_nontemporal_load(&srcs[i + 4 + g]);
        int s2 = __builtin_nontemporal_load(&srcs[i + 8 + g]);
        int s3 = __builtin_nontemporal_load(&srcs[i + 12 + g]);
        bf16x8 v0 = hv[(size_t)s0 * 16 + c];
        bf16x8 v1 = hv[(size_t)s1 * 16 + c];
        bf16x8 v2 = hv[(size_t)s2 * 16 + c];
        bf16x8 v3 = hv[(size_t)s3 * 16 + c];
#pragma unroll
        for (int j = 0; j < 8; ++j) {
            a[j] += (float)v0[j] + (float)v2[j];
            b2[j] += (float)v1[j] + (float)v3[j];
        }
    }
    for (; i + 8 <= end; i += 8) {
        int s0 = __builtin_nontemporal_load(&srcs[i + g]);
        int s1 = __builtin_nontemporal_load(&srcs[i + 4 + g]);
        bf16x8 v0 = hv[(size_t)s0 * 16 + c];
        bf16x8 v1 = hv[(size_t)s1 * 16 + c];
#pragma unroll
        for (int j = 0; j < 8; ++j) { a[j] += (float)v0[j]; b2[j] += (float)v1[j]; }
    }
    for (; i < end; i += 4) {
        if (i + g < end) {
            int s = __builtin_nontemporal_load(&srcs[i + g]);
            bf16x8 v = hv[(size_t)s * 16 + c];
#pragma unroll
            for (int j = 0; j < 8; ++j) a[j] += (float)v[j];
        }
    }
#pragma unroll
    for (int j = 0; j < 8; ++j) a[j] += b2[j];
#pragma unroll
    for (int j = 0; j < 8; ++j) a[j] += __shfl_xor(a[j], 16);
#pragma unroll
    for (int j = 0; j < 8; ++j) a[j] += __shfl_xor(a[j], 32);

    if (g == 0) {
        bf16x8 whi, wlo;
#pragma unroll
        for (int j = 0; j < 8; ++j) {
            float v = a[j] + (float)sh[j] + (float)sl[j];
            __bf16 h = (__bf16)v;
            whi[j] = h;
            wlo[j] = (__bf16)(v - (float)h);
        }
        ((bf16x8*)ohi)[(size_t)node * 16 + c] = whi;
        ((bf16x8*)olo)[(size_t)node * 16 + c] = wlo;
    }
}

// ===========================================================================
// Mid-layer GEMM (r10, retained): 64x64, K=128, stage-W-once + barrier-free.
// ===========================================================================
__global__ __launch_bounds__(256) void gemm64(
    const __bf16* __restrict__ Ahi, const __bf16* __restrict__ Alo,
    const __bf16* __restrict__ Wthi, const __bf16* __restrict__ Wtlo,
    const float* __restrict__ bias, __bf16* __restrict__ Ohi,
    __bf16* __restrict__ Olo, int M) {
    __shared__ __align__(16) char smem[32768];
    __bf16* sWhi = (__bf16*)smem;
    __bf16* sWlo = (__bf16*)(smem + 16384);

    int tid = threadIdx.x;
    int row0 = (blockIdx.x >> 1) * 64;
    int n0 = (blockIdx.x & 1) * 64;
    int wave = tid >> 6;
    int l = tid & 63;
    int m16 = l & 15;
    int q = l >> 4;
    int garow = min(row0 + wave * 16 + m16, M - 1);

#pragma unroll
    for (int it = 0; it < 4; ++it) {
        int lin = it * 2048 + tid * 8;
        int row = lin >> 7, k = lin & 127;
        int off = row * 128 + (((k >> 3) ^ (row & 7)) << 3);
        *(bf16x8*)(sWhi + off) = *(const bf16x8*)&Wthi[(size_t)(n0 + row) * 128 + k];
        *(bf16x8*)(sWlo + off) = *(const bf16x8*)&Wtlo[(size_t)(n0 + row) * 128 + k];
    }
    __syncthreads();

    floatx4 acc[4];
#pragma unroll
    for (int t = 0; t < 4; ++t) acc[t] = (floatx4){0.f, 0.f, 0.f, 0.f};

#pragma unroll
    for (int fs = 0; fs < 4; ++fs) {
        int kk = fs * 32 + q * 8;
        bf16x8 ahi = *(const bf16x8*)&Ahi[(size_t)garow * 128 + kk];
        bf16x8 alo = *(const bf16x8*)&Alo[(size_t)garow * 128 + kk];
#pragma unroll
        for (int t = 0; t < 4; ++t) {
            int n = t * 16 + m16;
            int soff = n * 128 + (((kk >> 3) ^ (n & 7)) << 3);
            bf16x8 bhi = *(bf16x8*)(sWhi + soff);
            bf16x8 blo = *(bf16x8*)(sWlo + soff);
            acc[t] = __builtin_amdgcn_mfma_f32_16x16x32_bf16(ahi, bhi, acc[t], 0, 0, 0);
            acc[t] = __builtin_amdgcn_mfma_f32_16x16x32_bf16(alo, bhi, acc[t], 0, 0, 0);
            acc[t] = __builtin_amdgcn_mfma_f32_16x16x32_bf16(ahi, blo, acc[t], 0, 0, 0);
        }
    }

    __syncthreads();
    float* eps = (float*)smem;
#pragma unroll
    for (int t = 0; t < 4; ++t) {
        float bb = bias[n0 + t * 16 + m16];
#pragma unroll
        for (int i = 0; i < 4; ++i) {
            int row = wave * 16 + q * 4 + i;
            eps[row * 68 + t * 16 + m16] = fmaxf(acc[t][i] + bb, 0.f);
        }
    }
    __syncthreads();
#pragma unroll
    for (int it = 0; it < 4; ++it) {
        int lin = it * 1024 + tid * 4;
        int row = lin >> 6, col = lin & 63;
        int g = row0 + row;
        if (g < M) {
            float4 v = *(float4*)(eps + row * 68 + col);
            bf16x4 hi, lo;
            float vv[4] = {v.x, v.y, v.z, v.w};
#pragma unroll
            for (int j = 0; j < 4; ++j) {
                __bf16 h = (__bf16)vv[j];
                hi[j] = h;
                lo[j] = (__bf16)(vv[j] - (float)h);
            }
            *(bf16x4*)&Ohi[(size_t)g * 128 + n0 + col] = hi;
            *(bf16x4*)&Olo[(size_t)g * 128 + n0 + col] = lo;
        }
    }
}

// ===========================================================================
// Final layer: stage-W-once barrier-free GEMM (64 rows x 128 cols, K=128)
// + fused output layer + log_softmax (epilogue math identical to r5-proven).
// W 128x128 hi/lo = 64KB staged once; 3 barriers total.
// ===========================================================================
__global__ __launch_bounds__(256) void gemm_out_once(
    const __bf16* __restrict__ Ahi, const __bf16* __restrict__ Alo,
    const __bf16* __restrict__ Wthi, const __bf16* __restrict__ Wtlo,
    const float* __restrict__ bias,
    const float* __restrict__ Wout, const float* __restrict__ bout,
    float* __restrict__ out, int M) {
    __shared__ __align__(16) char smem[65536];
    __bf16* sWhi = (__bf16*)smem;                // 128x128 = 32KB
    __bf16* sWlo = (__bf16*)(smem + 32768);      // 32KB

    int tid = threadIdx.x;
    int row0 = blockIdx.x * 64;
    int wave = tid >> 6;
    int l = tid & 63;
    int m16 = l & 15;
    int q = l >> 4;
    int garow = min(row0 + wave * 16 + m16, M - 1);

    // stage W once (128 cols x 128 k, hi+lo)
#pragma unroll
    for (int it = 0; it < 8; ++it) {
        int lin = it * 2048 + tid * 8;
        int wr = lin >> 7, k = lin & 127;
        int off = wr * 128 + (((k >> 3) ^ (wr & 7)) << 3);
        *(bf16x8*)(sWhi + off) = *(const bf16x8*)&Wthi[(size_t)wr * 128 + k];
        *(bf16x8*)(sWlo + off) = *(const bf16x8*)&Wtlo[(size_t)wr * 128 + k];
    }
    __syncthreads();

    floatx4 acc[8];
#pragma unroll
    for (int t = 0; t < 8; ++t) acc[t] = (floatx4){0.f, 0.f, 0.f, 0.f};

    // barrier-free k-loop: 4 fragment-steps of 32 k
#pragma unroll
    for (int fs = 0; fs < 4; ++fs) {
        int kk = fs * 32 + q * 8;
        bf16x8 ahi = *(const bf16x8*)&Ahi[(size_t)garow * 128 + kk];
        bf16x8 alo = *(const bf16x8*)&Alo[(size_t)garow * 128 + kk];
#pragma unroll
        for (int t = 0; t < 8; ++t) {
            int n = t * 16 + m16;
            int soff = n * 128 + (((kk >> 3) ^ (n & 7)) << 3);
            bf16x8 bhi = *(bf16x8*)(sWhi + soff);
            bf16x8 blo = *(bf16x8*)(sWlo + soff);
            acc[t] = __builtin_amdgcn_mfma_f32_16x16x32_bf16(ahi, bhi, acc[t], 0, 0, 0);
            acc[t] = __builtin_amdgcn_mfma_f32_16x16x32_bf16(alo, bhi, acc[t], 0, 0, 0);
            acc[t] = __builtin_amdgcn_mfma_f32_16x16x32_bf16(ahi, blo, acc[t], 0, 0, 0);
        }
    }

    // epilogue A: bias + relu into fp32 LDS (reuses W region; stride 132)
    __syncthreads();
    float* eps = (float*)smem;                    // 64*132*4 = 33792 B
    float* sWo = (float*)(smem + 34816);          // 128*40*4 = 20480 B
    float* sb  = (float*)(smem + 55296);          // 160 B
#pragma unroll
    for (int t = 0; t < 8; ++t) {
        int col = t * 16 + m16;
        float bb = bias[col];
#pragma unroll
        for (int i = 0; i < 4; ++i) {
            int row = wave * 16 + q * 4 + i;
            eps[row * 132 + col] = fmaxf(acc[t][i] + bb, 0.f);
        }
    }
    for (int i = tid; i < 128 * NCLASS; i += 256) sWo[i] = Wout[i];
    if (tid < NCLASS) sb[tid] = bout[tid];
    __syncthreads();

    // epilogue B: logits + log_softmax. 4 lanes/row, 10 classes/lane.
    int r = tid >> 2;
    int cg = tid & 3;
    float z[10];
#pragma unroll
    for (int j = 0; j < 10; ++j) z[j] = sb[cg * 10 + j];
    for (int k = 0; k < 128; ++k) {
        float a = eps[r * 132 + k];
#pragma unroll
        for (int j = 0; j < 10; ++j) z[j] += a * sWo[k * NCLASS + cg * 10 + j];
    }
    float m = z[0];
#pragma unroll
    for (int j = 1; j < 10; ++j) m = fmaxf(m, z[j]);
    m = fmaxf(m, __shfl_xor(m, 1));
    m = fmaxf(m, __shfl_xor(m, 2));
    float s = 0.f;
#pragma unroll
    for (int j = 0; j < 10; ++j) s += expf(z[j] - m);
    s += __shfl_xor(s, 1);
    s += __shfl_xor(s, 2);
    float lse = m + logf(s);
    int row = row0 + r;
    if (row < M) {
#pragma unroll
        for (int j = 0; j < 10; ++j) out[(size_t)row * NCLASS + cg * 10 + j] = z[j] - lse;
    }
}

// ===========================================================================
extern "C" void kernel_launch(void* const* d_in, const int* in_sizes, int n_in,
                              void* d_out, int out_size, void* d_ws, size_t ws_size,
                              hipStream_t stream) {
    const float* x      = (const float*)d_in[0];
    const int*   esrc   = (const int*)d_in[1];
    const int*   edst   = (const int*)d_in[2];
    const float* W_in   = (const float*)d_in[3];
    const float* b_in   = (const float*)d_in[4];
    const float* W_mlps = (const float*)d_in[5];
    const float* b_mlps = (const float*)d_in[6];
    const float* W_out  = (const float*)d_in[7];
    const float* b_out  = (const float*)d_in[8];
    float* out = (float*)d_out;

    int N = in_sizes[0] / NFEAT;  // 50000
    int E = in_sizes[1];          // 800000
    int nbuck = (N + 255) >> 8;   // 196

    // workspace carve (~81 MB)
    char* ws = (char*)d_ws;
    size_t hb = (((size_t)N * NHID * sizeof(__bf16)) + 255) & ~(size_t)255;  // 12.8MB
    __bf16* h_hi_a = (__bf16*)ws;
    __bf16* h_lo_a = (__bf16*)(ws + hb);
    __bf16* h_hi_b = (__bf16*)(ws + 2 * hb);
    __bf16* h_lo_b = (__bf16*)(ws + 3 * hb);
    __bf16* sum_hi = (__bf16*)(ws + 4 * hb);
    __bf16* sum_lo = (__bf16*)(ws + 5 * hb);
    // bdata aliases sum_hi's slot: used only during CSR build
    unsigned int* bdata = (unsigned int*)(ws + 4 * hb);
    char* ip = ws + 6 * hb;
    int* row_ptr = (int*)ip;  ip += (((size_t)(N + 1) * 4) + 255) & ~(size_t)255;
    int* srcs    = (int*)ip;  ip += (((size_t)E * 4) + 255) & ~(size_t)255;
    int* bucket_counts = (int*)ip;  ip += 1024;
    int* bucket_start  = (int*)ip;  ip += 1024;
    int* bucket_cursor = (int*)ip;  ip += 1024;
    __bf16* Wt_in_hi   = (__bf16*)ip;  ip += 128 * NFEAT * 2;
    __bf16* Wt_in_lo   = (__bf16*)ip;  ip += 128 * NFEAT * 2;
    __bf16* Wt_mlps_hi = (__bf16*)ip;  ip += 3 * 128 * NHID * 2;
    __bf16* Wt_mlps_lo = (__bf16*)ip;  ip += 3 * 128 * NHID * 2;

    int eb4 = (E + 4095) / 4096;  // 196
    int gb = (N + 63) / 64;       // 782

    // ---- CSR build + weight prep ----
    hipMemsetAsync(bucket_counts, 0, 1024, stream);
    hist_transpose<<<eb4 + 320, 256, 0, stream>>>(edst, bucket_counts, E, eb4, nbuck,
                                                  W_in, W_mlps, Wt_in_hi, Wt_in_lo,
                                                  Wt_mlps_hi, Wt_mlps_lo);
    bucket_scan<<<1, 256, 0, stream>>>(bucket_counts, bucket_start, bucket_cursor,
                                       row_ptr, nbuck, E, N);
    bucket_scatter<<<eb4, 256, 0, stream>>>(esrc, edst, bucket_cursor, bdata, E, nbuck);
    // ---- finalize || input-layer GEMM (stage-W-once) ----
    fin_gemmin64<<<nbuck + gb * 2, 256, 0, stream>>>(bdata, bucket_start, row_ptr, srcs,
                                                     N, nbuck, x, Wt_in_hi, Wt_in_lo,
                                                     b_in, h_hi_a, h_lo_a);

    // ---- GIN layers 0,1 ----
    __bf16* cur_hi = h_hi_a; __bf16* cur_lo = h_lo_a;
    __bf16* nxt_hi = h_hi_b; __bf16* nxt_lo = h_lo_b;
    for (int i = 0; i < 2; ++i) {
        aggregate_fused<<<(N + 3) / 4, 256, 0, stream>>>(cur_hi, cur_lo, row_ptr, srcs,
                                                         sum_hi, sum_lo, N);
        gemm64<<<gb * 2, 256, 0, stream>>>(
            sum_hi, sum_lo,
            Wt_mlps_hi + (size_t)i * 128 * NHID, Wt_mlps_lo + (size_t)i * 128 * NHID,
            b_mlps + (size_t)i * NHID, nxt_hi, nxt_lo, N);
        __bf16* t;
        t = cur_hi; cur_hi = nxt_hi; nxt_hi = t;
        t = cur_lo; cur_lo = nxt_lo; nxt_lo = t;
    }

    // ---- GIN layer 2 fused with output layer + log_softmax ----
    aggregate_fused<<<(N + 3) / 4, 256, 0, stream>>>(cur_hi, cur_lo, row_ptr, srcs,
                                                     sum_hi, sum_lo, N);
    gemm_out_once<<<gb, 256, 0, stream>>>(sum_hi, sum_lo,
                                          Wt_mlps_hi + (size_t)2 * 128 * NHID,
                                          Wt_mlps_lo + (size_t)2 * 128 * NHID,
                                          b_mlps + (size_t)2 * NHID,
                                          W_out, b_out, out, N);
}

// Round 12
// 311.173 us; speedup vs baseline: 1.3947x; 1.0353x over previous
//
#include <hip/hip_runtime.h>
#include <math.h>

#define NHID 128
#define NFEAT 256
#define NCLASS 40

typedef __bf16 bf16x8 __attribute__((ext_vector_type(8)));
typedef __bf16 bf16x4 __attribute__((ext_vector_type(4)));
typedef float floatx4 __attribute__((ext_vector_type(4)));

// ===========================================================================
// CSR build via 2-level bucketed counting sort.
// Bucket = dst >> 8; record = (dst&255)<<16 | src  (N <= 65536).
// Dispatch A: hist (blocks [0,eb4)) || weight transpose (blocks [eb4,eb4+320)).
// ===========================================================================
__global__ __launch_bounds__(256) void hist_transpose(
    const int* __restrict__ edst, int* __restrict__ bucket_counts, int E, int eb4,
    int nbuck,
    const float* __restrict__ Win, const float* __restrict__ Wmlps,
    __bf16* __restrict__ dInHi, __bf16* __restrict__ dInLo,
    __bf16* __restrict__ dMlHi, __bf16* __restrict__ dMlLo) {
    __shared__ int lh[256];
    int tid = threadIdx.x;
    int bid = blockIdx.x;
    if (bid < eb4) {
        lh[tid] = 0;
        __syncthreads();
        int base = bid * 4096;
#pragma unroll
        for (int k = 0; k < 16; ++k) {
            int e = base + k * 256 + tid;
            if (e < E) atomicAdd(&lh[edst[e] >> 8], 1);
        }
        __syncthreads();
        if (tid < nbuck && lh[tid]) atomicAdd(&bucket_counts[tid], lh[tid]);
    } else {
        const int TOT_IN = 128 * NFEAT;      // 32768
        const int TOT_ML = 3 * 128 * NHID;   // 49152
        int i = (bid - eb4) * 256 + tid;
        if (i < TOT_IN) {
            int n = i / NFEAT;
            int k = i - n * NFEAT;
            float v = Win[(size_t)k * 128 + n];
            __bf16 h = (__bf16)v;
            dInHi[i] = h;
            dInLo[i] = (__bf16)(v - (float)h);
        } else if (i < TOT_IN + TOT_ML) {
            int r = i - TOT_IN;
            int per = 128 * NHID;
            int l = r / per;
            int rr = r - l * per;
            int n = rr / NHID;
            int k = rr - n * NHID;
            float v = Wmlps[(size_t)l * per + (size_t)k * 128 + n];
            __bf16 h = (__bf16)v;
            dMlHi[r] = h;
            dMlLo[r] = (__bf16)(v - (float)h);
        }
    }
}

__global__ __launch_bounds__(256) void bucket_scan(const int* __restrict__ counts,
                                                   int* __restrict__ start,
                                                   int* __restrict__ cursor,
                                                   int* __restrict__ row_ptr,
                                                   int nbuck, int E, int N) {
    __shared__ int lds[256];
    int tid = threadIdx.x;
    int v = (tid < nbuck) ? counts[tid] : 0;
    lds[tid] = v;
    __syncthreads();
    for (int off = 1; off < 256; off <<= 1) {
        int t = (tid >= off) ? lds[tid - off] : 0;
        __syncthreads();
        lds[tid] += t;
        __syncthreads();
    }
    int excl = lds[tid] - v;
    if (tid < nbuck) { start[tid] = excl; cursor[tid] = excl; }
    if (tid == 0) { start[nbuck] = E; row_ptr[N] = E; }
}

__global__ __launch_bounds__(256) void bucket_scatter(const int* __restrict__ esrc,
                                                      const int* __restrict__ edst,
                                                      int* __restrict__ cursor,
                                                      unsigned int* __restrict__ bdata,
                                                      int E, int nbuck) {
    __shared__ int lh[256];
    __shared__ int lbase[256];
    int tid = threadIdx.x;
    lh[tid] = 0;
    __syncthreads();
    int base = blockIdx.x * 4096;
    unsigned int recs[16];
    short bks[16];
    short lofs[16];
#pragma unroll
    for (int k = 0; k < 16; ++k) {
        int e = base + k * 256 + tid;
        bks[k] = -1;
        if (e < E) {
            int d = edst[e];
            int s = esrc[e];
            int b = d >> 8;
            recs[k] = ((unsigned int)(d & 255) << 16) | (unsigned int)s;
            bks[k] = (short)b;
            lofs[k] = (short)atomicAdd(&lh[b], 1);
        }
    }
    __syncthreads();
    if (tid < nbuck && lh[tid]) lbase[tid] = atomicAdd(&cursor[tid], lh[tid]);
    __syncthreads();
#pragma unroll
    for (int k = 0; k < 16; ++k) {
        if (bks[k] >= 0) bdata[lbase[bks[k]] + lofs[k]] = recs[k];
    }
}

// ===========================================================================
// Dispatch D: FINALIZE (blocks [0,nbuck)) || GEMM_IN (blocks [nbuck,..)).
// gemm_in64: stage-W-once barrier-free GEMM, 64x64, K=256.
// h output is HI-ONLY (h_lo eliminated: gather reads hi; self-term tolerates
// bf16 rounding as 1 of ~17 already-rounded terms).
// ===========================================================================
__global__ __launch_bounds__(256) void fin_gemmin64(
    const unsigned int* __restrict__ bdata, const int* __restrict__ start,
    int* __restrict__ row_ptr, int* __restrict__ srcs, int N, int nbuck,
    const float* __restrict__ Af,
    const __bf16* __restrict__ Wthi, const __bf16* __restrict__ Wtlo,
    const float* __restrict__ bias, __bf16* __restrict__ Ohi) {
    __shared__ __align__(16) char smem[65536];
    int tid = threadIdx.x;
    if ((int)blockIdx.x < nbuck) {
        int* hist = (int*)smem;
        int* cur  = (int*)(smem + 1024);
        int b = blockIdx.x;
        int s0 = start[b];
        int cnt = start[b + 1] - s0;
        hist[tid] = 0;
        __syncthreads();
        for (int i = tid; i < cnt; i += 256) atomicAdd(&hist[bdata[s0 + i] >> 16], 1);
        __syncthreads();
        int v0 = hist[tid];
        __syncthreads();
        for (int off = 1; off < 256; off <<= 1) {
            int t = (tid >= off) ? hist[tid - off] : 0;
            __syncthreads();
            hist[tid] += t;
            __syncthreads();
        }
        int excl = hist[tid] - v0;
        cur[tid] = excl;
        int node = b * 256 + tid;
        if (node < N) row_ptr[node] = s0 + excl;
        __syncthreads();
        for (int i = tid; i < cnt; i += 256) {
            unsigned int r = bdata[s0 + i];
            int p = atomicAdd(&cur[r >> 16], 1);
            srcs[s0 + p] = (int)(r & 0xffffu);
        }
        return;
    }
    // ---------------- gemm_in64 ----------------
    __bf16* sWhi = (__bf16*)smem;                // 64x256 = 32KB
    __bf16* sWlo = (__bf16*)(smem + 32768);      // 32KB
    int bix = (int)blockIdx.x - nbuck;
    int row0 = (bix >> 1) * 64;
    int n0 = (bix & 1) * 64;
    int wave = tid >> 6;
    int l = tid & 63;
    int m16 = l & 15;
    int q = l >> 4;
    int garow = min(row0 + wave * 16 + m16, N - 1);

    // stage W once (64 cols x 256 k, hi+lo)
#pragma unroll
    for (int it = 0; it < 8; ++it) {
        int lin = it * 2048 + tid * 8;
        int wr = lin >> 8, k = lin & 255;
        int off = wr * 256 + (((k >> 3) ^ (wr & 7)) << 3);
        *(bf16x8*)(sWhi + off) = *(const bf16x8*)&Wthi[(size_t)(n0 + wr) * 256 + k];
        *(bf16x8*)(sWlo + off) = *(const bf16x8*)&Wtlo[(size_t)(n0 + wr) * 256 + k];
    }
    __syncthreads();

    floatx4 acc[4];
#pragma unroll
    for (int t = 0; t < 4; ++t) acc[t] = (floatx4){0.f, 0.f, 0.f, 0.f};

    // barrier-free k-loop: 8 fragment-steps of 32 k
#pragma unroll
    for (int fs = 0; fs < 8; ++fs) {
        int kk = fs * 32 + q * 8;
        float4 v0 = *(const float4*)&Af[(size_t)garow * 256 + kk];
        float4 v1 = *(const float4*)&Af[(size_t)garow * 256 + kk + 4];
        float sv[8] = {v0.x, v0.y, v0.z, v0.w, v1.x, v1.y, v1.z, v1.w};
        bf16x8 ahi, alo;
#pragma unroll
        for (int j = 0; j < 8; ++j) {
            __bf16 h = (__bf16)sv[j];
            ahi[j] = h;
            alo[j] = (__bf16)(sv[j] - (float)h);
        }
#pragma unroll
        for (int t = 0; t < 4; ++t) {
            int n = t * 16 + m16;
            int soff = n * 256 + (((kk >> 3) ^ (n & 7)) << 3);
            bf16x8 bhi = *(bf16x8*)(sWhi + soff);
            bf16x8 blo = *(bf16x8*)(sWlo + soff);
            acc[t] = __builtin_amdgcn_mfma_f32_16x16x32_bf16(ahi, bhi, acc[t], 0, 0, 0);
            acc[t] = __builtin_amdgcn_mfma_f32_16x16x32_bf16(alo, bhi, acc[t], 0, 0, 0);
            acc[t] = __builtin_amdgcn_mfma_f32_16x16x32_bf16(ahi, blo, acc[t], 0, 0, 0);
        }
    }

    // epilogue: reuse W LDS as 64x68 fp32 buffer; HI-only store
    __syncthreads();
    float* eps = (float*)smem;
#pragma unroll
    for (int t = 0; t < 4; ++t) {
        float bb = bias[n0 + t * 16 + m16];
#pragma unroll
        for (int i = 0; i < 4; ++i) {
            int row = wave * 16 + q * 4 + i;
            eps[row * 68 + t * 16 + m16] = fmaxf(acc[t][i] + bb, 0.f);
        }
    }
    __syncthreads();
#pragma unroll
    for (int it = 0; it < 4; ++it) {
        int lin = it * 1024 + tid * 4;
        int row = lin >> 6, col = lin & 63;
        int g = row0 + row;
        if (g < N) {
            float4 v = *(float4*)(eps + row * 68 + col);
            bf16x4 hi;
            float vv[4] = {v.x, v.y, v.z, v.w};
#pragma unroll
            for (int j = 0; j < 4; ++j) hi[j] = (__bf16)vv[j];
            *(bf16x4*)&Ohi[(size_t)g * 128 + n0 + col] = hi;
        }
    }
}

// ===========================================================================
// Fused aggregate: sum = h[node] + sum_{src in CSR} h[src]  (h is hi-only),
// written as bf16 hi/lo pair (sum's lo carries real precision for the GEMM).
// One wave/node; 16 lanes x 16B row; 16 edges (4 gathers) in flight.
// ===========================================================================
__global__ __launch_bounds__(256) void aggregate_fused(const __bf16* __restrict__ hhi,
                                                       const int* __restrict__ row_ptr,
                                                       const int* __restrict__ srcs,
                                                       __bf16* __restrict__ ohi,
                                                       __bf16* __restrict__ olo, int N) {
    int tid = threadIdx.x;
    int node = blockIdx.x * 4 + (tid >> 6);
    if (node >= N) return;
    int lane = tid & 63;
    int g = lane >> 4;
    int c = lane & 15;
    int beg = row_ptr[node];
    int end = row_ptr[node + 1];
    const bf16x8* hv = (const bf16x8*)hhi;

    bf16x8 sh = hv[(size_t)node * 16 + c];

    float a[8], b2[8];
#pragma unroll
    for (int j = 0; j < 8; ++j) { a[j] = 0.f; b2[j] = 0.f; }

    int i = beg;
    for (; i + 16 <= end; i += 16) {
        int s0 = __builtin_nontemporal_load(&srcs[i + g]);
        int s1 = __builtin_nontemporal_load(&srcs[i + 4 + g]);
        int s2 = __builtin_nontemporal_load(&srcs[i + 8 + g]);
        int s3 = __builtin_nontemporal_load(&srcs[i + 12 + g]);
        bf16x8 v0 = hv[(size_t)s0 * 16 + c];
        bf16x8 v1 = hv[(size_t)s1 * 16 + c];
        bf16x8 v2 = hv[(size_t)s2 * 16 + c];
        bf16x8 v3 = hv[(size_t)s3 * 16 + c];
#pragma unroll
        for (int j = 0; j < 8; ++j) {
            a[j] += (float)v0[j] + (float)v2[j];
            b2[j] += (float)v1[j] + (float)v3[j];
        }
    }
    for (; i + 8 <= end; i += 8) {
        int s0 = __builtin_nontemporal_load(&srcs[i + g]);
        int s1 = __builtin_nontemporal_load(&srcs[i + 4 + g]);
        bf16x8 v0 = hv[(size_t)s0 * 16 + c];
        bf16x8 v1 = hv[(size_t)s1 * 16 + c];
#pragma unroll
        for (int j = 0; j < 8; ++j) { a[j] += (float)v0[j]; b2[j] += (float)v1[j]; }
    }
    for (; i < end; i += 4) {
        if (i + g < end) {
            int s = __builtin_nontemporal_load(&srcs[i + g]);
            bf16x8 v = hv[(size_t)s * 16 + c];
#pragma unroll
            for (int j = 0; j < 8; ++j) a[j] += (float)v[j];
        }
    }
#pragma unroll
    for (int j = 0; j < 8; ++j) a[j] += b2[j];
#pragma unroll
    for (int j = 0; j < 8; ++j) a[j] += __shfl_xor(a[j], 16);
#pragma unroll
    for (int j = 0; j < 8; ++j) a[j] += __shfl_xor(a[j], 32);

    if (g == 0) {
        bf16x8 whi, wlo;
#pragma unroll
        for (int j = 0; j < 8; ++j) {
            float v = a[j] + (float)sh[j];
            __bf16 h = (__bf16)v;
            whi[j] = h;
            wlo[j] = (__bf16)(v - (float)h);
        }
        ((bf16x8*)ohi)[(size_t)node * 16 + c] = whi;
        ((bf16x8*)olo)[(size_t)node * 16 + c] = wlo;
    }
}

// ===========================================================================
// Mid-layer GEMM: 64x64, K=128, stage-W-once + barrier-free. HI-only h out.
// ===========================================================================
__global__ __launch_bounds__(256) void gemm64(
    const __bf16* __restrict__ Ahi, const __bf16* __restrict__ Alo,
    const __bf16* __restrict__ Wthi, const __bf16* __restrict__ Wtlo,
    const float* __restrict__ bias, __bf16* __restrict__ Ohi, int M) {
    __shared__ __align__(16) char smem[32768];
    __bf16* sWhi = (__bf16*)smem;
    __bf16* sWlo = (__bf16*)(smem + 16384);

    int tid = threadIdx.x;
    int row0 = (blockIdx.x >> 1) * 64;
    int n0 = (blockIdx.x & 1) * 64;
    int wave = tid >> 6;
    int l = tid & 63;
    int m16 = l & 15;
    int q = l >> 4;
    int garow = min(row0 + wave * 16 + m16, M - 1);

#pragma unroll
    for (int it = 0; it < 4; ++it) {
        int lin = it * 2048 + tid * 8;
        int row = lin >> 7, k = lin & 127;
        int off = row * 128 + (((k >> 3) ^ (row & 7)) << 3);
        *(bf16x8*)(sWhi + off) = *(const bf16x8*)&Wthi[(size_t)(n0 + row) * 128 + k];
        *(bf16x8*)(sWlo + off) = *(const bf16x8*)&Wtlo[(size_t)(n0 + row) * 128 + k];
    }
    __syncthreads();

    floatx4 acc[4];
#pragma unroll
    for (int t = 0; t < 4; ++t) acc[t] = (floatx4){0.f, 0.f, 0.f, 0.f};

#pragma unroll
    for (int fs = 0; fs < 4; ++fs) {
        int kk = fs * 32 + q * 8;
        bf16x8 ahi = *(const bf16x8*)&Ahi[(size_t)garow * 128 + kk];
        bf16x8 alo = *(const bf16x8*)&Alo[(size_t)garow * 128 + kk];
#pragma unroll
        for (int t = 0; t < 4; ++t) {
            int n = t * 16 + m16;
            int soff = n * 128 + (((kk >> 3) ^ (n & 7)) << 3);
            bf16x8 bhi = *(bf16x8*)(sWhi + soff);
            bf16x8 blo = *(bf16x8*)(sWlo + soff);
            acc[t] = __builtin_amdgcn_mfma_f32_16x16x32_bf16(ahi, bhi, acc[t], 0, 0, 0);
            acc[t] = __builtin_amdgcn_mfma_f32_16x16x32_bf16(alo, bhi, acc[t], 0, 0, 0);
            acc[t] = __builtin_amdgcn_mfma_f32_16x16x32_bf16(ahi, blo, acc[t], 0, 0, 0);
        }
    }

    __syncthreads();
    float* eps = (float*)smem;
#pragma unroll
    for (int t = 0; t < 4; ++t) {
        float bb = bias[n0 + t * 16 + m16];
#pragma unroll
        for (int i = 0; i < 4; ++i) {
            int row = wave * 16 + q * 4 + i;
            eps[row * 68 + t * 16 + m16] = fmaxf(acc[t][i] + bb, 0.f);
        }
    }
    __syncthreads();
#pragma unroll
    for (int it = 0; it < 4; ++it) {
        int lin = it * 1024 + tid * 4;
        int row = lin >> 6, col = lin & 63;
        int g = row0 + row;
        if (g < M) {
            float4 v = *(float4*)(eps + row * 68 + col);
            bf16x4 hi;
            float vv[4] = {v.x, v.y, v.z, v.w};
#pragma unroll
            for (int j = 0; j < 4; ++j) hi[j] = (__bf16)vv[j];
            *(bf16x4*)&Ohi[(size_t)g * 128 + n0 + col] = hi;
        }
    }
}

// ===========================================================================
// Final layer: stage-W-once barrier-free GEMM (64x128, K=128) + fused output
// layer + log_softmax. A = sum hi/lo (unchanged — sum's lo carries precision).
// ===========================================================================
__global__ __launch_bounds__(256) void gemm_out_once(
    const __bf16* __restrict__ Ahi, const __bf16* __restrict__ Alo,
    const __bf16* __restrict__ Wthi, const __bf16* __restrict__ Wtlo,
    const float* __restrict__ bias,
    const float* __restrict__ Wout, const float* __restrict__ bout,
    float* __restrict__ out, int M) {
    __shared__ __align__(16) char smem[65536];
    __bf16* sWhi = (__bf16*)smem;                // 128x128 = 32KB
    __bf16* sWlo = (__bf16*)(smem + 32768);      // 32KB

    int tid = threadIdx.x;
    int row0 = blockIdx.x * 64;
    int wave = tid >> 6;
    int l = tid & 63;
    int m16 = l & 15;
    int q = l >> 4;
    int garow = min(row0 + wave * 16 + m16, M - 1);

#pragma unroll
    for (int it = 0; it < 8; ++it) {
        int lin = it * 2048 + tid * 8;
        int wr = lin >> 7, k = lin & 127;
        int off = wr * 128 + (((k >> 3) ^ (wr & 7)) << 3);
        *(bf16x8*)(sWhi + off) = *(const bf16x8*)&Wthi[(size_t)wr * 128 + k];
        *(bf16x8*)(sWlo + off) = *(const bf16x8*)&Wtlo[(size_t)wr * 128 + k];
    }
    __syncthreads();

    floatx4 acc[8];
#pragma unroll
    for (int t = 0; t < 8; ++t) acc[t] = (floatx4){0.f, 0.f, 0.f, 0.f};

#pragma unroll
    for (int fs = 0; fs < 4; ++fs) {
        int kk = fs * 32 + q * 8;
        bf16x8 ahi = *(const bf16x8*)&Ahi[(size_t)garow * 128 + kk];
        bf16x8 alo = *(const bf16x8*)&Alo[(size_t)garow * 128 + kk];
#pragma unroll
        for (int t = 0; t < 8; ++t) {
            int n = t * 16 + m16;
            int soff = n * 128 + (((kk >> 3) ^ (n & 7)) << 3);
            bf16x8 bhi = *(bf16x8*)(sWhi + soff);
            bf16x8 blo = *(bf16x8*)(sWlo + soff);
            acc[t] = __builtin_amdgcn_mfma_f32_16x16x32_bf16(ahi, bhi, acc[t], 0, 0, 0);
            acc[t] = __builtin_amdgcn_mfma_f32_16x16x32_bf16(alo, bhi, acc[t], 0, 0, 0);
            acc[t] = __builtin_amdgcn_mfma_f32_16x16x32_bf16(ahi, blo, acc[t], 0, 0, 0);
        }
    }

    __syncthreads();
    float* eps = (float*)smem;                    // 64*132*4 = 33792 B
    float* sWo = (float*)(smem + 34816);          // 128*40*4 = 20480 B
    float* sb  = (float*)(smem + 55296);          // 160 B
#pragma unroll
    for (int t = 0; t < 8; ++t) {
        int col = t * 16 + m16;
        float bb = bias[col];
#pragma unroll
        for (int i = 0; i < 4; ++i) {
            int row = wave * 16 + q * 4 + i;
            eps[row * 132 + col] = fmaxf(acc[t][i] + bb, 0.f);
        }
    }
    for (int i = tid; i < 128 * NCLASS; i += 256) sWo[i] = Wout[i];
    if (tid < NCLASS) sb[tid] = bout[tid];
    __syncthreads();

    int r = tid >> 2;
    int cg = tid & 3;
    float z[10];
#pragma unroll
    for (int j = 0; j < 10; ++j) z[j] = sb[cg * 10 + j];
    for (int k = 0; k < 128; ++k) {
        float a = eps[r * 132 + k];
#pragma unroll
        for (int j = 0; j < 10; ++j) z[j] += a * sWo[k * NCLASS + cg * 10 + j];
    }
    float m = z[0];
#pragma unroll
    for (int j = 1; j < 10; ++j) m = fmaxf(m, z[j]);
    m = fmaxf(m, __shfl_xor(m, 1));
    m = fmaxf(m, __shfl_xor(m, 2));
    float s = 0.f;
#pragma unroll
    for (int j = 0; j < 10; ++j) s += expf(z[j] - m);
    s += __shfl_xor(s, 1);
    s += __shfl_xor(s, 2);
    float lse = m + logf(s);
    int row = row0 + r;
    if (row < M) {
#pragma unroll
        for (int j = 0; j < 10; ++j) out[(size_t)row * NCLASS + cg * 10 + j] = z[j] - lse;
    }
}

// ===========================================================================
extern "C" void kernel_launch(void* const* d_in, const int* in_sizes, int n_in,
                              void* d_out, int out_size, void* d_ws, size_t ws_size,
                              hipStream_t stream) {
    const float* x      = (const float*)d_in[0];
    const int*   esrc   = (const int*)d_in[1];
    const int*   edst   = (const int*)d_in[2];
    const float* W_in   = (const float*)d_in[3];
    const float* b_in   = (const float*)d_in[4];
    const float* W_mlps = (const float*)d_in[5];
    const float* b_mlps = (const float*)d_in[6];
    const float* W_out  = (const float*)d_in[7];
    const float* b_out  = (const float*)d_in[8];
    float* out = (float*)d_out;

    int N = in_sizes[0] / NFEAT;  // 50000
    int E = in_sizes[1];          // 800000
    int nbuck = (N + 255) >> 8;   // 196

    // workspace carve (~81 MB; offsets unchanged from r11)
    char* ws = (char*)d_ws;
    size_t hb = (((size_t)N * NHID * sizeof(__bf16)) + 255) & ~(size_t)255;  // 12.8MB
    __bf16* h_hi_a = (__bf16*)ws;
    __bf16* h_hi_b = (__bf16*)(ws + 2 * hb);
    __bf16* sum_hi = (__bf16*)(ws + 4 * hb);
    __bf16* sum_lo = (__bf16*)(ws + 5 * hb);
    // bdata aliases sum_hi's slot: used only during CSR build
    unsigned int* bdata = (unsigned int*)(ws + 4 * hb);
    char* ip = ws + 6 * hb;
    int* row_ptr = (int*)ip;  ip += (((size_t)(N + 1) * 4) + 255) & ~(size_t)255;
    int* srcs    = (int*)ip;  ip += (((size_t)E * 4) + 255) & ~(size_t)255;
    int* bucket_counts = (int*)ip;  ip += 1024;
    int* bucket_start  = (int*)ip;  ip += 1024;
    int* bucket_cursor = (int*)ip;  ip += 1024;
    __bf16* Wt_in_hi   = (__bf16*)ip;  ip += 128 * NFEAT * 2;
    __bf16* Wt_in_lo   = (__bf16*)ip;  ip += 128 * NFEAT * 2;
    __bf16* Wt_mlps_hi = (__bf16*)ip;  ip += 3 * 128 * NHID * 2;
    __bf16* Wt_mlps_lo = (__bf16*)ip;  ip += 3 * 128 * NHID * 2;

    int eb4 = (E + 4095) / 4096;  // 196
    int gb = (N + 63) / 64;       // 782

    // ---- CSR build + weight prep ----
    hipMemsetAsync(bucket_counts, 0, 1024, stream);
    hist_transpose<<<eb4 + 320, 256, 0, stream>>>(edst, bucket_counts, E, eb4, nbuck,
                                                  W_in, W_mlps, Wt_in_hi, Wt_in_lo,
                                                  Wt_mlps_hi, Wt_mlps_lo);
    bucket_scan<<<1, 256, 0, stream>>>(bucket_counts, bucket_start, bucket_cursor,
                                       row_ptr, nbuck, E, N);
    bucket_scatter<<<eb4, 256, 0, stream>>>(esrc, edst, bucket_cursor, bdata, E, nbuck);
    // ---- finalize || input-layer GEMM (hi-only h) ----
    fin_gemmin64<<<nbuck + gb * 2, 256, 0, stream>>>(bdata, bucket_start, row_ptr, srcs,
                                                     N, nbuck, x, Wt_in_hi, Wt_in_lo,
                                                     b_in, h_hi_a);

    // ---- GIN layers 0,1 ----
    __bf16* cur_hi = h_hi_a;
    __bf16* nxt_hi = h_hi_b;
    for (int i = 0; i < 2; ++i) {
        aggregate_fused<<<(N + 3) / 4, 256, 0, stream>>>(cur_hi, row_ptr, srcs,
                                                         sum_hi, sum_lo, N);
        gemm64<<<gb * 2, 256, 0, stream>>>(
            sum_hi, sum_lo,
            Wt_mlps_hi + (size_t)i * 128 * NHID, Wt_mlps_lo + (size_t)i * 128 * NHID,
            b_mlps + (size_t)i * NHID, nxt_hi, N);
        __bf16* t = cur_hi; cur_hi = nxt_hi; nxt_hi = t;
    }

    // ---- GIN layer 2 fused with output layer + log_softmax ----
    aggregate_fused<<<(N + 3) / 4, 256, 0, stream>>>(cur_hi, row_ptr, srcs,
                                                     sum_hi, sum_lo, N);
    gemm_out_once<<<gb, 256, 0, stream>>>(sum_hi, sum_lo,
                                          Wt_mlps_hi + (size_t)2 * 128 * NHID,
                                          Wt_mlps_lo + (size_t)2 * 128 * NHID,
                                          b_mlps + (size_t)2 * NHID,
                                          W_out, b_out, out, N);
}

// Round 13
// 279.004 us; speedup vs baseline: 1.5555x; 1.1153x over previous
//
#include <hip/hip_runtime.h>
#include <math.h>

#define NHID 128
#define NFEAT 256
#define NCLASS 40

typedef __bf16 bf16x8 __attribute__((ext_vector_type(8)));
typedef __bf16 bf16x4 __attribute__((ext_vector_type(4)));
typedef float floatx4 __attribute__((ext_vector_type(4)));

// ===========================================================================
// CSR build via 2-level bucketed counting sort.
// Bucket = dst >> 8; record = (dst&255)<<16 | src  (N <= 65536).
// Dispatch A: hist (blocks [0,eb4)) || weight transpose (blocks [eb4,eb4+320)).
// Weights are bf16 SINGLE precision now (lo-streams dropped; r12-validated
// error class ~0.4%/stream).
// ===========================================================================
__global__ __launch_bounds__(256) void hist_transpose(
    const int* __restrict__ edst, int* __restrict__ bucket_counts, int E, int eb4,
    int nbuck,
    const float* __restrict__ Win, const float* __restrict__ Wmlps,
    __bf16* __restrict__ dInHi, __bf16* __restrict__ dMlHi) {
    __shared__ int lh[256];
    int tid = threadIdx.x;
    int bid = blockIdx.x;
    if (bid < eb4) {
        lh[tid] = 0;
        __syncthreads();
        int base = bid * 4096;
#pragma unroll
        for (int k = 0; k < 16; ++k) {
            int e = base + k * 256 + tid;
            if (e < E) atomicAdd(&lh[edst[e] >> 8], 1);
        }
        __syncthreads();
        if (tid < nbuck && lh[tid]) atomicAdd(&bucket_counts[tid], lh[tid]);
    } else {
        const int TOT_IN = 128 * NFEAT;      // 32768
        const int TOT_ML = 3 * 128 * NHID;   // 49152
        int i = (bid - eb4) * 256 + tid;
        if (i < TOT_IN) {
            int n = i / NFEAT;
            int k = i - n * NFEAT;
            dInHi[i] = (__bf16)Win[(size_t)k * 128 + n];
        } else if (i < TOT_IN + TOT_ML) {
            int r = i - TOT_IN;
            int per = 128 * NHID;
            int l = r / per;
            int rr = r - l * per;
            int n = rr / NHID;
            int k = rr - n * NHID;
            dMlHi[r] = (__bf16)Wmlps[(size_t)l * per + (size_t)k * 128 + n];
        }
    }
}

__global__ __launch_bounds__(256) void bucket_scan(const int* __restrict__ counts,
                                                   int* __restrict__ start,
                                                   int* __restrict__ cursor,
                                                   int* __restrict__ row_ptr,
                                                   int nbuck, int E, int N) {
    __shared__ int lds[256];
    int tid = threadIdx.x;
    int v = (tid < nbuck) ? counts[tid] : 0;
    lds[tid] = v;
    __syncthreads();
    for (int off = 1; off < 256; off <<= 1) {
        int t = (tid >= off) ? lds[tid - off] : 0;
        __syncthreads();
        lds[tid] += t;
        __syncthreads();
    }
    int excl = lds[tid] - v;
    if (tid < nbuck) { start[tid] = excl; cursor[tid] = excl; }
    if (tid == 0) { start[nbuck] = E; row_ptr[N] = E; }
}

__global__ __launch_bounds__(256) void bucket_scatter(const int* __restrict__ esrc,
                                                      const int* __restrict__ edst,
                                                      int* __restrict__ cursor,
                                                      unsigned int* __restrict__ bdata,
                                                      int E, int nbuck) {
    __shared__ int lh[256];
    __shared__ int lbase[256];
    int tid = threadIdx.x;
    lh[tid] = 0;
    __syncthreads();
    int base = blockIdx.x * 4096;
    unsigned int recs[16];
    short bks[16];
    short lofs[16];
#pragma unroll
    for (int k = 0; k < 16; ++k) {
        int e = base + k * 256 + tid;
        bks[k] = -1;
        if (e < E) {
            int d = edst[e];
            int s = esrc[e];
            int b = d >> 8;
            recs[k] = ((unsigned int)(d & 255) << 16) | (unsigned int)s;
            bks[k] = (short)b;
            lofs[k] = (short)atomicAdd(&lh[b], 1);
        }
    }
    __syncthreads();
    if (tid < nbuck && lh[tid]) lbase[tid] = atomicAdd(&cursor[tid], lh[tid]);
    __syncthreads();
#pragma unroll
    for (int k = 0; k < 16; ++k) {
        if (bks[k] >= 0) bdata[lbase[bks[k]] + lofs[k]] = recs[k];
    }
}

// ===========================================================================
// Dispatch D: FINALIZE (blocks [0,nbuck)) || GEMM_IN (blocks [nbuck,..+gb)).
// gemm_in_full: 64 rows x FULL 128 cols, K=256. W bf16 single = 64KB staged
// once; x read ONCE (was twice); A keeps in-register fp32->hi/lo split
// (2 MFMA per fragment); barrier-free k-loop; h output hi-only bf16.
// ===========================================================================
__global__ __launch_bounds__(256) void fin_gemmin64(
    const unsigned int* __restrict__ bdata, const int* __restrict__ start,
    int* __restrict__ row_ptr, int* __restrict__ srcs, int N, int nbuck,
    const float* __restrict__ Af,
    const __bf16* __restrict__ Wthi,
    const float* __restrict__ bias, __bf16* __restrict__ Ohi) {
    __shared__ __align__(16) char smem[65536];
    int tid = threadIdx.x;
    if ((int)blockIdx.x < nbuck) {
        int* hist = (int*)smem;
        int* cur  = (int*)(smem + 1024);
        int b = blockIdx.x;
        int s0 = start[b];
        int cnt = start[b + 1] - s0;
        hist[tid] = 0;
        __syncthreads();
        for (int i = tid; i < cnt; i += 256) atomicAdd(&hist[bdata[s0 + i] >> 16], 1);
        __syncthreads();
        int v0 = hist[tid];
        __syncthreads();
        for (int off = 1; off < 256; off <<= 1) {
            int t = (tid >= off) ? hist[tid - off] : 0;
            __syncthreads();
            hist[tid] += t;
            __syncthreads();
        }
        int excl = hist[tid] - v0;
        cur[tid] = excl;
        int node = b * 256 + tid;
        if (node < N) row_ptr[node] = s0 + excl;
        __syncthreads();
        for (int i = tid; i < cnt; i += 256) {
            unsigned int r = bdata[s0 + i];
            int p = atomicAdd(&cur[r >> 16], 1);
            srcs[s0 + p] = (int)(r & 0xffffu);
        }
        return;
    }
    // ---------------- gemm_in_full ----------------
    __bf16* sW = (__bf16*)smem;                  // 128 cols x 256 k = 64KB
    int bix = (int)blockIdx.x - nbuck;
    int row0 = bix * 64;
    int wave = tid >> 6;
    int l = tid & 63;
    int m16 = l & 15;
    int q = l >> 4;
    int garow = min(row0 + wave * 16 + m16, N - 1);

    // stage W once
#pragma unroll
    for (int it = 0; it < 16; ++it) {
        int lin = it * 2048 + tid * 8;
        int wr = lin >> 8, k = lin & 255;
        int off = wr * 256 + (((k >> 3) ^ (wr & 7)) << 3);
        *(bf16x8*)(sW + off) = *(const bf16x8*)&Wthi[(size_t)wr * 256 + k];
    }
    __syncthreads();

    floatx4 acc[8];
#pragma unroll
    for (int t = 0; t < 8; ++t) acc[t] = (floatx4){0.f, 0.f, 0.f, 0.f};

    // barrier-free k-loop: 8 fragment-steps of 32 k
#pragma unroll
    for (int fs = 0; fs < 8; ++fs) {
        int kk = fs * 32 + q * 8;
        float4 v0 = *(const float4*)&Af[(size_t)garow * 256 + kk];
        float4 v1 = *(const float4*)&Af[(size_t)garow * 256 + kk + 4];
        float sv[8] = {v0.x, v0.y, v0.z, v0.w, v1.x, v1.y, v1.z, v1.w};
        bf16x8 ahi, alo;
#pragma unroll
        for (int j = 0; j < 8; ++j) {
            __bf16 h = (__bf16)sv[j];
            ahi[j] = h;
            alo[j] = (__bf16)(sv[j] - (float)h);
        }
#pragma unroll
        for (int t = 0; t < 8; ++t) {
            int n = t * 16 + m16;
            int soff = n * 256 + (((kk >> 3) ^ (n & 7)) << 3);
            bf16x8 b = *(bf16x8*)(sW + soff);
            acc[t] = __builtin_amdgcn_mfma_f32_16x16x32_bf16(ahi, b, acc[t], 0, 0, 0);
            acc[t] = __builtin_amdgcn_mfma_f32_16x16x32_bf16(alo, b, acc[t], 0, 0, 0);
        }
    }

    // epilogue: reuse W LDS as 64x132 fp32 buffer; hi-only bf16 store
    __syncthreads();
    float* eps = (float*)smem;
#pragma unroll
    for (int t = 0; t < 8; ++t) {
        int col = t * 16 + m16;
        float bb = bias[col];
#pragma unroll
        for (int i = 0; i < 4; ++i) {
            int row = wave * 16 + q * 4 + i;
            eps[row * 132 + col] = fmaxf(acc[t][i] + bb, 0.f);
        }
    }
    __syncthreads();
#pragma unroll
    for (int it = 0; it < 8; ++it) {
        int lin = it * 1024 + tid * 4;
        int row = lin >> 7, col = lin & 127;
        int g = row0 + row;
        if (g < N) {
            float4 v = *(float4*)(eps + row * 132 + col);
            bf16x4 hi;
            float vv[4] = {v.x, v.y, v.z, v.w};
#pragma unroll
            for (int j = 0; j < 4; ++j) hi[j] = (__bf16)vv[j];
            *(bf16x4*)&Ohi[(size_t)g * 128 + col] = hi;
        }
    }
}

// ===========================================================================
// Fused aggregate: sum = h[node] + sum_{src in CSR} h[src]  (h hi-only),
// written hi-only bf16 (sum_lo dropped; r12-validated error class).
// One wave/node; 16 lanes x 16B row; 16 edges (4 gathers) in flight.
// ===========================================================================
__global__ __launch_bounds__(256) void aggregate_fused(const __bf16* __restrict__ hhi,
                                                       const int* __restrict__ row_ptr,
                                                       const int* __restrict__ srcs,
                                                       __bf16* __restrict__ ohi, int N) {
    int tid = threadIdx.x;
    int node = blockIdx.x * 4 + (tid >> 6);
    if (node >= N) return;
    int lane = tid & 63;
    int g = lane >> 4;
    int c = lane & 15;
    int beg = row_ptr[node];
    int end = row_ptr[node + 1];
    const bf16x8* hv = (const bf16x8*)hhi;

    bf16x8 sh = hv[(size_t)node * 16 + c];

    float a[8], b2[8];
#pragma unroll
    for (int j = 0; j < 8; ++j) { a[j] = 0.f; b2[j] = 0.f; }

    int i = beg;
    for (; i + 16 <= end; i += 16) {
        int s0 = __builtin_nontemporal_load(&srcs[i + g]);
        int s1 = __builtin_nontemporal_load(&srcs[i + 4 + g]);
        int s2 = __builtin_nontemporal_load(&srcs[i + 8 + g]);
        int s3 = __builtin_nontemporal_load(&srcs[i + 12 + g]);
        bf16x8 v0 = hv[(size_t)s0 * 16 + c];
        bf16x8 v1 = hv[(size_t)s1 * 16 + c];
        bf16x8 v2 = hv[(size_t)s2 * 16 + c];
        bf16x8 v3 = hv[(size_t)s3 * 16 + c];
#pragma unroll
        for (int j = 0; j < 8; ++j) {
            a[j] += (float)v0[j] + (float)v2[j];
            b2[j] += (float)v1[j] + (float)v3[j];
        }
    }
    for (; i + 8 <= end; i += 8) {
        int s0 = __builtin_nontemporal_load(&srcs[i + g]);
        int s1 = __builtin_nontemporal_load(&srcs[i + 4 + g]);
        bf16x8 v0 = hv[(size_t)s0 * 16 + c];
        bf16x8 v1 = hv[(size_t)s1 * 16 + c];
#pragma unroll
        for (int j = 0; j < 8; ++j) { a[j] += (float)v0[j]; b2[j] += (float)v1[j]; }
    }
    for (; i < end; i += 4) {
        if (i + g < end) {
            int s = __builtin_nontemporal_load(&srcs[i + g]);
            bf16x8 v = hv[(size_t)s * 16 + c];
#pragma unroll
            for (int j = 0; j < 8; ++j) a[j] += (float)v[j];
        }
    }
#pragma unroll
    for (int j = 0; j < 8; ++j) a[j] += b2[j];
#pragma unroll
    for (int j = 0; j < 8; ++j) a[j] += __shfl_xor(a[j], 16);
#pragma unroll
    for (int j = 0; j < 8; ++j) a[j] += __shfl_xor(a[j], 32);

    if (g == 0) {
        bf16x8 whi;
#pragma unroll
        for (int j = 0; j < 8; ++j) whi[j] = (__bf16)(a[j] + (float)sh[j]);
        ((bf16x8*)ohi)[(size_t)node * 16 + c] = whi;
    }
}

// ===========================================================================
// Mid-layer GEMM: 64 rows x FULL 128 cols, K=128, plain bf16 single-MFMA.
// W = 32KB staged once; sum read ONCE; barrier-free k-loop; hi-only h out.
// ===========================================================================
__global__ __launch_bounds__(256) void gemm64(
    const __bf16* __restrict__ Ahi,
    const __bf16* __restrict__ Wthi,
    const float* __restrict__ bias, __bf16* __restrict__ Ohi, int M) {
    __shared__ __align__(16) char smem[34816];
    __bf16* sW = (__bf16*)smem;                  // 128 x 128 = 32KB

    int tid = threadIdx.x;
    int row0 = blockIdx.x * 64;
    int wave = tid >> 6;
    int l = tid & 63;
    int m16 = l & 15;
    int q = l >> 4;
    int garow = min(row0 + wave * 16 + m16, M - 1);

#pragma unroll
    for (int it = 0; it < 8; ++it) {
        int lin = it * 2048 + tid * 8;
        int wr = lin >> 7, k = lin & 127;
        int off = wr * 128 + (((k >> 3) ^ (wr & 7)) << 3);
        *(bf16x8*)(sW + off) = *(const bf16x8*)&Wthi[(size_t)wr * 128 + k];
    }
    __syncthreads();

    floatx4 acc[8];
#pragma unroll
    for (int t = 0; t < 8; ++t) acc[t] = (floatx4){0.f, 0.f, 0.f, 0.f};

#pragma unroll
    for (int fs = 0; fs < 4; ++fs) {
        int kk = fs * 32 + q * 8;
        bf16x8 a = *(const bf16x8*)&Ahi[(size_t)garow * 128 + kk];
#pragma unroll
        for (int t = 0; t < 8; ++t) {
            int n = t * 16 + m16;
            int soff = n * 128 + (((kk >> 3) ^ (n & 7)) << 3);
            bf16x8 b = *(bf16x8*)(sW + soff);
            acc[t] = __builtin_amdgcn_mfma_f32_16x16x32_bf16(a, b, acc[t], 0, 0, 0);
        }
    }

    __syncthreads();
    float* eps = (float*)smem;  // 64*132*4 = 33792 <= 34816
#pragma unroll
    for (int t = 0; t < 8; ++t) {
        int col = t * 16 + m16;
        float bb = bias[col];
#pragma unroll
        for (int i = 0; i < 4; ++i) {
            int row = wave * 16 + q * 4 + i;
            eps[row * 132 + col] = fmaxf(acc[t][i] + bb, 0.f);
        }
    }
    __syncthreads();
#pragma unroll
    for (int it = 0; it < 8; ++it) {
        int lin = it * 1024 + tid * 4;
        int row = lin >> 7, col = lin & 127;
        int g = row0 + row;
        if (g < M) {
            float4 v = *(float4*)(eps + row * 132 + col);
            bf16x4 hi;
            float vv[4] = {v.x, v.y, v.z, v.w};
#pragma unroll
            for (int j = 0; j < 4; ++j) hi[j] = (__bf16)vv[j];
            *(bf16x4*)&Ohi[(size_t)g * 128 + col] = hi;
        }
    }
}

// ===========================================================================
// Final layer: plain-bf16 stage-W-once GEMM (64x128, K=128) + fused output
// layer + log_softmax. A = sum hi-only.
// ===========================================================================
__global__ __launch_bounds__(256) void gemm_out_once(
    const __bf16* __restrict__ Ahi,
    const __bf16* __restrict__ Wthi,
    const float* __restrict__ bias,
    const float* __restrict__ Wout, const float* __restrict__ bout,
    float* __restrict__ out, int M) {
    __shared__ __align__(16) char smem[57344];
    __bf16* sW = (__bf16*)smem;                  // 128 x 128 = 32KB

    int tid = threadIdx.x;
    int row0 = blockIdx.x * 64;
    int wave = tid >> 6;
    int l = tid & 63;
    int m16 = l & 15;
    int q = l >> 4;
    int garow = min(row0 + wave * 16 + m16, M - 1);

#pragma unroll
    for (int it = 0; it < 8; ++it) {
        int lin = it * 2048 + tid * 8;
        int wr = lin >> 7, k = lin & 127;
        int off = wr * 128 + (((k >> 3) ^ (wr & 7)) << 3);
        *(bf16x8*)(sW + off) = *(const bf16x8*)&Wthi[(size_t)wr * 128 + k];
    }
    __syncthreads();

    floatx4 acc[8];
#pragma unroll
    for (int t = 0; t < 8; ++t) acc[t] = (floatx4){0.f, 0.f, 0.f, 0.f};

#pragma unroll
    for (int fs = 0; fs < 4; ++fs) {
        int kk = fs * 32 + q * 8;
        bf16x8 a = *(const bf16x8*)&Ahi[(size_t)garow * 128 + kk];
#pragma unroll
        for (int t = 0; t < 8; ++t) {
            int n = t * 16 + m16;
            int soff = n * 128 + (((kk >> 3) ^ (n & 7)) << 3);
            bf16x8 b = *(bf16x8*)(sW + soff);
            acc[t] = __builtin_amdgcn_mfma_f32_16x16x32_bf16(a, b, acc[t], 0, 0, 0);
        }
    }

    __syncthreads();
    float* eps = (float*)smem;                    // 64*132*4 = 33792 B
    float* sWo = (float*)(smem + 34816);          // 128*40*4 = 20480 B
    float* sb  = (float*)(smem + 55296);          // 160 B
#pragma unroll
    for (int t = 0; t < 8; ++t) {
        int col = t * 16 + m16;
        float bb = bias[col];
#pragma unroll
        for (int i = 0; i < 4; ++i) {
            int row = wave * 16 + q * 4 + i;
            eps[row * 132 + col] = fmaxf(acc[t][i] + bb, 0.f);
        }
    }
    for (int i = tid; i < 128 * NCLASS; i += 256) sWo[i] = Wout[i];
    if (tid < NCLASS) sb[tid] = bout[tid];
    __syncthreads();

    int r = tid >> 2;
    int cg = tid & 3;
    float z[10];
#pragma unroll
    for (int j = 0; j < 10; ++j) z[j] = sb[cg * 10 + j];
    for (int k = 0; k < 128; ++k) {
        float a = eps[r * 132 + k];
#pragma unroll
        for (int j = 0; j < 10; ++j) z[j] += a * sWo[k * NCLASS + cg * 10 + j];
    }
    float m = z[0];
#pragma unroll
    for (int j = 1; j < 10; ++j) m = fmaxf(m, z[j]);
    m = fmaxf(m, __shfl_xor(m, 1));
    m = fmaxf(m, __shfl_xor(m, 2));
    float s = 0.f;
#pragma unroll
    for (int j = 0; j < 10; ++j) s += expf(z[j] - m);
    s += __shfl_xor(s, 1);
    s += __shfl_xor(s, 2);
    float lse = m + logf(s);
    int row = row0 + r;
    if (row < M) {
#pragma unroll
        for (int j = 0; j < 10; ++j) out[(size_t)row * NCLASS + cg * 10 + j] = z[j] - lse;
    }
}

// ===========================================================================
extern "C" void kernel_launch(void* const* d_in, const int* in_sizes, int n_in,
                              void* d_out, int out_size, void* d_ws, size_t ws_size,
                              hipStream_t stream) {
    const float* x      = (const float*)d_in[0];
    const int*   esrc   = (const int*)d_in[1];
    const int*   edst   = (const int*)d_in[2];
    const float* W_in   = (const float*)d_in[3];
    const float* b_in   = (const float*)d_in[4];
    const float* W_mlps = (const float*)d_in[5];
    const float* b_mlps = (const float*)d_in[6];
    const float* W_out  = (const float*)d_in[7];
    const float* b_out  = (const float*)d_in[8];
    float* out = (float*)d_out;

    int N = in_sizes[0] / NFEAT;  // 50000
    int E = in_sizes[1];          // 800000
    int nbuck = (N + 255) >> 8;   // 196

    // workspace carve
    char* ws = (char*)d_ws;
    size_t hb = (((size_t)N * NHID * sizeof(__bf16)) + 255) & ~(size_t)255;  // 12.8MB
    __bf16* h_hi_a = (__bf16*)ws;
    __bf16* h_hi_b = (__bf16*)(ws + 2 * hb);
    __bf16* sum_hi = (__bf16*)(ws + 4 * hb);
    // bdata aliases sum_hi's slot: used only during CSR build
    unsigned int* bdata = (unsigned int*)(ws + 4 * hb);
    char* ip = ws + 6 * hb;
    int* row_ptr = (int*)ip;  ip += (((size_t)(N + 1) * 4) + 255) & ~(size_t)255;
    int* srcs    = (int*)ip;  ip += (((size_t)E * 4) + 255) & ~(size_t)255;
    int* bucket_counts = (int*)ip;  ip += 1024;
    int* bucket_start  = (int*)ip;  ip += 1024;
    int* bucket_cursor = (int*)ip;  ip += 1024;
    __bf16* Wt_in_hi   = (__bf16*)ip;  ip += 128 * NFEAT * 2;
    __bf16* Wt_mlps_hi = (__bf16*)ip;  ip += 3 * 128 * NHID * 2;

    int eb4 = (E + 4095) / 4096;  // 196
    int gb = (N + 63) / 64;       // 782

    // ---- CSR build + weight prep ----
    hipMemsetAsync(bucket_counts, 0, 1024, stream);
    hist_transpose<<<eb4 + 320, 256, 0, stream>>>(edst, bucket_counts, E, eb4, nbuck,
                                                  W_in, W_mlps, Wt_in_hi, Wt_mlps_hi);
    bucket_scan<<<1, 256, 0, stream>>>(bucket_counts, bucket_start, bucket_cursor,
                                       row_ptr, nbuck, E, N);
    bucket_scatter<<<eb4, 256, 0, stream>>>(esrc, edst, bucket_cursor, bdata, E, nbuck);
    // ---- finalize || input-layer GEMM (x read once, W bf16) ----
    fin_gemmin64<<<nbuck + gb, 256, 0, stream>>>(bdata, bucket_start, row_ptr, srcs,
                                                 N, nbuck, x, Wt_in_hi, b_in, h_hi_a);

    // ---- GIN layers 0,1 ----
    __bf16* cur_hi = h_hi_a;
    __bf16* nxt_hi = h_hi_b;
    for (int i = 0; i < 2; ++i) {
        aggregate_fused<<<(N + 3) / 4, 256, 0, stream>>>(cur_hi, row_ptr, srcs,
                                                         sum_hi, N);
        gemm64<<<gb, 256, 0, stream>>>(
            sum_hi, Wt_mlps_hi + (size_t)i * 128 * NHID,
            b_mlps + (size_t)i * NHID, nxt_hi, N);
        __bf16* t = cur_hi; cur_hi = nxt_hi; nxt_hi = t;
    }

    // ---- GIN layer 2 fused with output layer + log_softmax ----
    aggregate_fused<<<(N + 3) / 4, 256, 0, stream>>>(cur_hi, row_ptr, srcs,
                                                     sum_hi, N);
    gemm_out_once<<<gb, 256, 0, stream>>>(sum_hi,
                                          Wt_mlps_hi + (size_t)2 * 128 * NHID,
                                          b_mlps + (size_t)2 * NHID,
                                          W_out, b_out, out, N);
}